// Round 18
// baseline (469.947 us; speedup 1.0000x reference)
//
#include <hip/hip_runtime.h>
#include <cstdint>

typedef __attribute__((ext_vector_type(8))) __bf16 bf16x8;
typedef __attribute__((ext_vector_type(4))) __bf16 bf16x4;
typedef __attribute__((ext_vector_type(4))) float f32x4;
typedef unsigned long long u64;

__device__ __forceinline__ void gld_lds16(const void* g, void* l) {
  __builtin_amdgcn_global_load_lds(
      (const __attribute__((address_space(1))) void*)g,
      (__attribute__((address_space(3))) void*)l, 16, 0, 0);
}

__device__ __forceinline__ float block_sum(float v, float* scr) {
#pragma unroll
  for (int off = 32; off > 0; off >>= 1) v += __shfl_down(v, off, 64);
  const int w = threadIdx.x >> 6;
  __syncthreads();
  if ((threadIdx.x & 63) == 0) scr[w] = v;
  __syncthreads();
  float s = 0.f;
  const int nw = blockDim.x >> 6;
  for (int i = 0; i < nw; ++i) s += scr[i];
  return s;
}

// fused N-value block reduction (256 threads = 4 waves), scr size >= 4*N
template <int N>
__device__ __forceinline__ void block_sumN(float* v, float* scr) {
#pragma unroll
  for (int i = 0; i < N; ++i)
#pragma unroll
    for (int m = 1; m < 64; m <<= 1) v[i] += __shfl_xor(v[i], m, 64);
  const int w = threadIdx.x >> 6;
  __syncthreads();
  if ((threadIdx.x & 63) == 0)
#pragma unroll
    for (int i = 0; i < N; ++i) scr[w * N + i] = v[i];
  __syncthreads();
#pragma unroll
  for (int i = 0; i < N; ++i) {
    float s = 0.f;
    for (int ww = 0; ww < 4; ++ww) s += scr[ww * N + i];
    v[i] = s;
  }
}

// fast gelu: A&S 7.1.26 erf (|err|<1.5e-7) + hw exp
__device__ __forceinline__ float gelu_fast(float x) {
  const float ax = fabsf(x) * 0.70710678118654752f;
  const float t = 1.f / (1.f + 0.3275911f * ax);
  const float e = __expf(-ax * ax);
  float poly = 1.061405429f;
  poly = poly * t - 1.453152027f;
  poly = poly * t + 1.421413741f;
  poly = poly * t - 0.284496736f;
  poly = poly * t + 0.254829592f;
  const float erfax = 1.f - poly * t * e;
  const float er = copysignf(erfax, x);
  return 0.5f * x * (1.f + er);
}

// combined weight casts: proj_w(2048 blk) | wf_w(6144 blk) | gate_w(1024 blk)
__global__ __launch_bounds__(256) void k_cast_weights(
    const float* __restrict__ pw, __bf16* __restrict__ w1b,
    const float* __restrict__ wfw, __bf16* __restrict__ wfwb,
    const float* __restrict__ gw, __bf16* __restrict__ gwb) {
  const int bid = blockIdx.x;
  const float* in;
  __bf16* out;
  long base;
  if (bid < 2048) { in = pw; out = w1b; base = (long)bid * 1024; }
  else if (bid < 8192) { in = wfw; out = wfwb; base = (long)(bid - 2048) * 1024; }
  else { in = gw; out = gwb; base = (long)(bid - 8192) * 1024; }
  const long i = base + threadIdx.x * 4;
  f32x4 v = *(const f32x4*)(in + i);
  bf16x4 o = {(__bf16)v[0], (__bf16)v[1], (__bf16)v[2], (__bf16)v[3]};
  *(bf16x4*)(out + i) = o;
}

__global__ __launch_bounds__(256) void k_cast_pad(const float* __restrict__ in,
                                                  __bf16* __restrict__ out,
                                                  int rows_real, int cols) {
  const long i = ((long)blockIdx.x * 256 + threadIdx.x) * 4;
  const int row = (int)(i / cols);
  const int col = (int)(i % cols);
  bf16x4 o;
  if (row < rows_real) {
    f32x4 v = *(const f32x4*)(in + (long)row * cols + col);
    o = (bf16x4){(__bf16)v[0], (__bf16)v[1], (__bf16)v[2], (__bf16)v[3]};
  } else {
    o = (bf16x4){(__bf16)0.f, (__bf16)0.f, (__bf16)0.f, (__bf16)0.f};
  }
  *(bf16x4*)(out + i) = o;
}

// ---------------- transpose 1024x1024 f32 ----------------
__global__ __launch_bounds__(256) void k_transpose1k(const float* __restrict__ in,
                                                     float* __restrict__ out) {
  __shared__ float t[32][33];
  const int tx = threadIdx.x & 31;
  const int ty = threadIdx.x >> 5;
  const int r0 = blockIdx.y * 32, c0 = blockIdx.x * 32;
#pragma unroll
  for (int k = 0; k < 4; ++k)
    t[ty + 8 * k][tx] = in[(long)(r0 + ty + 8 * k) * 1024 + c0 + tx];
  __syncthreads();
#pragma unroll
  for (int k = 0; k < 4; ++k)
    out[(long)(c0 + ty + 8 * k) * 1024 + r0 + tx] = t[tx][ty + 8 * k];
}

// ============ 256x256 8-wave BK=64 GEMM, 4-phase interleave + counted vmcnt ============
__global__ __launch_bounds__(512, 1) void k_gemm256_bt(
    const __bf16* __restrict__ A, const __bf16* __restrict__ B,
    const float* __restrict__ bias, __bf16* __restrict__ C,
    int M, int N, int K) {
  __shared__ __align__(16) __bf16 lds[2][2][256 * 64];  // [slot][mat][row*64+k]
  const int tid = threadIdx.x;
  const int lane = tid & 63;
  const int wid = tid >> 6;
  const int wr = wid >> 2;
  const int wc = wid & 3;
  const int gx = gridDim.x, gy = gridDim.y;
  const int lin = blockIdx.y * gx + blockIdx.x;
  const int xcd = lin & 7;
  const int local = lin >> 3;
  const int byq = gy >> 3;
  const int bx = local / byq;
  const int by = xcd * byq + (local % byq);
  const int m0 = by * 256, n0 = bx * 256;
  const int fr = lane & 15;
  const int fx = lane >> 4;
  const int px = lane & 7;

  const __bf16* Abase = A + (long)m0 * K;
  const __bf16* Bbase = B + (long)n0 * K;

  auto stage_q = [&](int slot, int kt, int mat, int half) {
    const __bf16* src = (mat ? Bbase : Abase) + kt * 64;
#pragma unroll
    for (int q = 0; q < 2; ++q) {
      const int idx = q * 512 + tid;
      const int r = idx >> 3;
      const int pblk = idx & 7;
      const int row = half * 128 + r;
      const int lblk = pblk ^ (r & 7);
      gld_lds16(src + (long)row * K + lblk * 8,
                (char*)&lds[slot][mat][row * 64 + pblk * 8]);
    }
  };
  auto frag = [&](int slot, int mat, int row, int ks) -> bf16x8 {
    return *(const bf16x8*)&lds[slot][mat][row * 64 + ((((ks << 2) + fx) ^ px) << 3)];
  };

  f32x4 acc[8][4] = {};
  const int nt = K >> 6;
  stage_q(0, 0, 0, 0);
  stage_q(0, 0, 0, 1);
  stage_q(0, 0, 1, 0);
  stage_q(0, 0, 1, 1);
  if (nt > 1) {
    stage_q(1, 1, 1, 0);
    stage_q(1, 1, 1, 1);
    asm volatile("s_waitcnt vmcnt(4)" ::: "memory");
  } else {
    asm volatile("s_waitcnt vmcnt(0)" ::: "memory");
  }
  __builtin_amdgcn_sched_barrier(0);
  __builtin_amdgcn_s_barrier();

  const int arow = wr * 128 + fr;
  const int brow = wc * 64 + fr;
  bf16x8 af[4][2], bl[2][2], bh[2][2];

  for (int t = 0; t < nt; ++t) {
    const int s = t & 1;
    if (t + 1 < nt) stage_q(s ^ 1, t + 1, 0, 0);
#pragma unroll
    for (int i = 0; i < 4; ++i) {
      af[i][0] = frag(s, 0, arow + i * 16, 0);
      af[i][1] = frag(s, 0, arow + i * 16, 1);
    }
#pragma unroll
    for (int j = 0; j < 2; ++j) {
      bl[j][0] = frag(s, 1, brow + j * 16, 0);
      bl[j][1] = frag(s, 1, brow + j * 16, 1);
    }
    __builtin_amdgcn_s_barrier();
    asm volatile("s_waitcnt lgkmcnt(0)" ::: "memory");
    __builtin_amdgcn_sched_barrier(0);
    __builtin_amdgcn_s_setprio(1);
#pragma unroll
    for (int i = 0; i < 4; ++i)
#pragma unroll
      for (int j = 0; j < 2; ++j) {
        acc[i][j] = __builtin_amdgcn_mfma_f32_16x16x32_bf16(af[i][0], bl[j][0], acc[i][j], 0, 0, 0);
        acc[i][j] = __builtin_amdgcn_mfma_f32_16x16x32_bf16(af[i][1], bl[j][1], acc[i][j], 0, 0, 0);
      }
    __builtin_amdgcn_s_setprio(0);
    __builtin_amdgcn_s_barrier();
    if (t + 1 < nt) stage_q(s ^ 1, t + 1, 0, 1);
#pragma unroll
    for (int j = 0; j < 2; ++j) {
      bh[j][0] = frag(s, 1, brow + (j + 2) * 16, 0);
      bh[j][1] = frag(s, 1, brow + (j + 2) * 16, 1);
    }
    __builtin_amdgcn_s_barrier();
    asm volatile("s_waitcnt lgkmcnt(0)" ::: "memory");
    __builtin_amdgcn_sched_barrier(0);
    __builtin_amdgcn_s_setprio(1);
#pragma unroll
    for (int i = 0; i < 4; ++i)
#pragma unroll
      for (int j = 0; j < 2; ++j) {
        acc[i][j + 2] = __builtin_amdgcn_mfma_f32_16x16x32_bf16(af[i][0], bh[j][0], acc[i][j + 2], 0, 0, 0);
        acc[i][j + 2] = __builtin_amdgcn_mfma_f32_16x16x32_bf16(af[i][1], bh[j][1], acc[i][j + 2], 0, 0, 0);
      }
    __builtin_amdgcn_s_setprio(0);
    __builtin_amdgcn_s_barrier();
    if (t + 2 < nt) stage_q(s, t + 2, 1, 0);
#pragma unroll
    for (int i = 0; i < 4; ++i) {
      af[i][0] = frag(s, 0, arow + (i + 4) * 16, 0);
      af[i][1] = frag(s, 0, arow + (i + 4) * 16, 1);
    }
    __builtin_amdgcn_s_barrier();
    asm volatile("s_waitcnt lgkmcnt(0)" ::: "memory");
    __builtin_amdgcn_sched_barrier(0);
    __builtin_amdgcn_s_setprio(1);
#pragma unroll
    for (int i = 0; i < 4; ++i)
#pragma unroll
      for (int j = 0; j < 2; ++j) {
        acc[i + 4][j + 2] = __builtin_amdgcn_mfma_f32_16x16x32_bf16(af[i][0], bh[j][0], acc[i + 4][j + 2], 0, 0, 0);
        acc[i + 4][j + 2] = __builtin_amdgcn_mfma_f32_16x16x32_bf16(af[i][1], bh[j][1], acc[i + 4][j + 2], 0, 0, 0);
      }
    __builtin_amdgcn_s_setprio(0);
    __builtin_amdgcn_s_barrier();
    if (t + 2 < nt) stage_q(s, t + 2, 1, 1);
    __builtin_amdgcn_s_barrier();
    __builtin_amdgcn_s_setprio(1);
#pragma unroll
    for (int i = 0; i < 4; ++i)
#pragma unroll
      for (int j = 0; j < 2; ++j) {
        acc[i + 4][j] = __builtin_amdgcn_mfma_f32_16x16x32_bf16(af[i][0], bl[j][0], acc[i + 4][j], 0, 0, 0);
        acc[i + 4][j] = __builtin_amdgcn_mfma_f32_16x16x32_bf16(af[i][1], bl[j][1], acc[i + 4][j], 0, 0, 0);
      }
    __builtin_amdgcn_s_setprio(0);
    if (t + 2 < nt) {
      asm volatile("s_waitcnt vmcnt(4)" ::: "memory");
    } else {
      asm volatile("s_waitcnt vmcnt(0)" ::: "memory");
    }
    __builtin_amdgcn_sched_barrier(0);
    __builtin_amdgcn_s_barrier();
  }

  // ---- epilogue: bounce C tile through dead staging LDS ----
  __bf16* cb = (__bf16*)&lds[0][0][0];
  const int lm0 = wr * 128 + fx * 4;
  const int lc0 = wc * 64 + fr;
#pragma unroll
  for (int j = 0; j < 4; ++j) {
    const float bv = bias[n0 + lc0 + j * 16];
#pragma unroll
    for (int im = 0; im < 8; ++im)
#pragma unroll
      for (int r = 0; r < 4; ++r)
        cb[(lm0 + im * 16 + r) * 256 + lc0 + j * 16] = (__bf16)(acc[im][j][r] + bv);
  }
  __syncthreads();
#pragma unroll
  for (int q = 0; q < 16; ++q) {
    const int idx = q * 512 + tid;
    const int row = idx >> 5;
    const int c8 = (idx & 31) * 8;
    *(f32x4*)(C + (long)(m0 + row) * N + n0 + c8) = *(const f32x4*)(cb + row * 256 + c8);
  }
}

// ---------------- GEMM: C = A @ B^T + bias (128-col tiles) ----------------
// EPI: 0 f32 store (LDS-bounce), 1 bf16 scatter (fallback), 6/7 gate streaming.
// AF32: A source is f32 (fused cast, reg-staged, T14 split). Requires BM==64.
template <int EPI, int BM, int AF32 = 0>
__global__ __launch_bounds__(256) void k_gemm_bt(
    const void* __restrict__ Ain, const __bf16* __restrict__ B,
    const float* __restrict__ bias, void* __restrict__ Cout,
    int M, int N, int K, int Nreal,
    float* __restrict__ msq, __bf16* __restrict__ magOut) {
  constexpr int MR = BM / 32;
  constexpr int STAGE_B = (2 * BM * 32 + 2 * 128 * 32) * 2;
  constexpr int CB_B = BM * 64 * 4;
  constexpr int SMEM_B = STAGE_B > CB_B ? STAGE_B : CB_B;
  __shared__ __align__(16) char smem[SMEM_B];
  __bf16* As = (__bf16*)smem;
  __bf16* Bs = (__bf16*)(smem + (size_t)2 * BM * 32 * 2);
  float* cb = (float*)smem;  // bounce region (BM x 64 f32)
  const int tid = threadIdx.x;
  const int lane = tid & 63;
  const int wid = tid >> 6;
  const int wr = wid >> 1, wc = wid & 1;

  const int gx = gridDim.x, gy = gridDim.y;
  const int nwg = gx * gy;
  int bx, by;
  if ((nwg & 7) == 0) {
    const int lin = blockIdx.y * gx + blockIdx.x;
    const int cpx = nwg >> 3;
    const int w = (lin & 7) * cpx + (lin >> 3);
    bx = w / gy;
    by = w % gy;
  } else {
    bx = blockIdx.x;
    by = blockIdx.y;
  }
  const int m0 = by * BM;
  const int n0 = bx * 128;
  const int frow = lane & 15;
  const int fk = (lane >> 4) * 8;
  f32x4 acc[MR][4] = {};

  const __bf16* Ab16 = (const __bf16*)Ain;
  const float* Af32 = (const float*)Ain;

  // stage B (gld_lds) and, when !AF32, A (gld_lds)
  auto stage = [&](int buf, int k0) {
    __bf16* Bsb = Bs + buf * 128 * 32;
    if (!AF32) {
      const __bf16* Ab = Ab16 + (long)m0 * K + k0;
      __bf16* Asb = As + buf * BM * 32;
#pragma unroll
      for (int q = 0; q < BM / 64; ++q) {
        const int idx = q * 256 + tid;
        const int row = idx >> 2;
        const int col = (idx & 3) * 8;
        gld_lds16(Ab + (long)row * K + col, (char*)Asb + idx * 16);
      }
    }
    const __bf16* Bb = B + (long)n0 * K + k0;
#pragma unroll
    for (int q = 0; q < 2; ++q) {
      const int idx = q * 256 + tid;
      const int row = idx >> 2;
      const int col = (idx & 3) * 8;
      gld_lds16(Bb + (long)row * K + col, (char*)Bsb + idx * 16);
    }
  };
  // AF32 A path: per-thread one 16B LDS chunk (8 bf16) from 32B f32 source
  auto loadA = [&](int k0, f32x4& a0, f32x4& a1) {
    const int row = tid >> 2;
    const int col = (tid & 3) * 8;
    const float* p = Af32 + (long)(m0 + row) * K + k0 + col;
    a0 = *(const f32x4*)p;
    a1 = *(const f32x4*)(p + 4);
  };
  auto writeA = [&](int buf, const f32x4& a0, const f32x4& a1) {
    bf16x8 v;
    v[0] = (__bf16)a0[0]; v[1] = (__bf16)a0[1]; v[2] = (__bf16)a0[2]; v[3] = (__bf16)a0[3];
    v[4] = (__bf16)a1[0]; v[5] = (__bf16)a1[1]; v[6] = (__bf16)a1[2]; v[7] = (__bf16)a1[3];
    *(bf16x8*)(As + buf * BM * 32 + tid * 8) = v;
  };

  const int nt = K >> 5;
  int cur = 0;
  f32x4 a0c, a1c, a0n, a1n;
  if (AF32) {
    loadA(0, a0c, a1c);
    stage(0, 0);
    writeA(0, a0c, a1c);
  } else {
    stage(0, 0);
  }
  __syncthreads();
  for (int t = 0; t < nt; ++t) {
    if (t + 1 < nt) {
      stage(cur ^ 1, (t + 1) << 5);
      if (AF32) loadA((t + 1) << 5, a0n, a1n);
    }
    bf16x8 af[MR], bfr[4];
#pragma unroll
    for (int i = 0; i < MR; ++i)
      af[i] = *(const bf16x8*)(As + cur * BM * 32 + (wr * (BM / 2) + i * 16 + frow) * 32 + fk);
#pragma unroll
    for (int i = 0; i < 4; ++i)
      bfr[i] = *(const bf16x8*)(Bs + cur * 128 * 32 + (wc * 64 + i * 16 + frow) * 32 + fk);
#pragma unroll
    for (int im = 0; im < MR; ++im)
#pragma unroll
      for (int in = 0; in < 4; ++in)
        acc[im][in] = __builtin_amdgcn_mfma_f32_16x16x32_bf16(af[im], bfr[in],
                                                              acc[im][in], 0, 0, 0);
    if (AF32 && t + 1 < nt) writeA(cur ^ 1, a0n, a1n);
    __syncthreads();
    cur ^= 1;
  }

  if (EPI == 0 || EPI == 6 || EPI == 7) {
#pragma unroll 1
    for (int h = 0; h < 2; ++h) {
      __syncthreads();
      if (wc == h) {
#pragma unroll
        for (int in = 0; in < 4; ++in) {
          const int col = n0 + h * 64 + in * 16 + frow;
          const float bv = (col < Nreal) ? bias[col] : 0.f;
          const int lcc = in * 16 + frow;
#pragma unroll
          for (int im = 0; im < MR; ++im)
#pragma unroll
            for (int r = 0; r < 4; ++r) {
              const float v = acc[im][in][r] + bv;
              float sv;
              if (EPI == 0) {
                sv = v;
              } else {
                const float f = 1.f / (1.f + __expf(-v)) + 0.1f;
                sv = f * f;
              }
              cb[(wr * (BM / 2) + (lane >> 4) * 4 + im * 16 + r) * 64 + lcc] = sv;
            }
        }
      }
      __syncthreads();
#pragma unroll
      for (int q = 0; q < BM / 16; ++q) {
        const int idx = q * 256 + tid;
        const int row = idx >> 4;
        const int c4 = (idx & 15) * 4;
        const int gc = n0 + h * 64 + c4;
        if (EPI == 0) {
          if (gc < Nreal)
            *(f32x4*)((float*)Cout + (long)(m0 + row) * Nreal + gc) =
                *(const f32x4*)(cb + row * 64 + c4);
        } else {
          const long gix = (long)(m0 + row) * Nreal + gc;
          f32x4 m = *(const f32x4*)(msq + gix);
          const f32x4 f2 = *(const f32x4*)(cb + row * 64 + c4);
          m[0] *= f2[0]; m[1] *= f2[1]; m[2] *= f2[2]; m[3] *= f2[3];
          *(f32x4*)(msq + gix) = m;
          if (EPI == 6) {
            bf16x4 mg = {(__bf16)sqrtf(m[0] + 1e-8f), (__bf16)sqrtf(m[1] + 1e-8f),
                         (__bf16)sqrtf(m[2] + 1e-8f), (__bf16)sqrtf(m[3] + 1e-8f)};
            *(bf16x4*)(magOut + gix) = mg;
          }
        }
      }
    }
  } else {
    const int crow0 = m0 + wr * (BM / 2) + (lane >> 4) * 4;
    const int ccol0 = n0 + wc * 64 + (lane & 15);
#pragma unroll
    for (int in = 0; in < 4; ++in) {
      const int col = ccol0 + in * 16;
      if (col >= Nreal) continue;
      const float bv = bias[col];
#pragma unroll
      for (int im = 0; im < MR; ++im) {
#pragma unroll
        for (int r = 0; r < 4; ++r) {
          const long row = crow0 + im * 16 + r;
          ((__bf16*)Cout)[row * Nreal + col] = (__bf16)(acc[im][in][r] + bv);
        }
      }
    }
  }
}

// ---------------- LN (over 1024) + gelu -> bf16 ----------------
__global__ __launch_bounds__(256) void k_ln_gelu(const float* __restrict__ y,
                                                 const float* __restrict__ g,
                                                 const float* __restrict__ b,
                                                 __bf16* __restrict__ h) {
  __shared__ float scr[8];
  const int tid = threadIdx.x;
  const long row = blockIdx.x;
  const float* yr = y + row * 1024;
  f32x4 v = *(const f32x4*)(yr + tid * 4);
  float ls = v[0] + v[1] + v[2] + v[3];
  const float mu = block_sum(ls, scr) * (1.f / 1024.f);
  float lss = 0.f;
#pragma unroll
  for (int j = 0; j < 4; ++j) {
    const float d = v[j] - mu;
    lss += d * d;
  }
  const float var = block_sum(lss, scr) * (1.f / 1024.f);
  const float rstd = rsqrtf(var + 1e-5f);
  bf16x4 o;
#pragma unroll
  for (int j = 0; j < 4; ++j) {
    const int c = tid * 4 + j;
    const float t = (v[j] - mu) * rstd * g[c] + b[c];
    o[j] = (__bf16)gelu_fast(t);
  }
  *(bf16x4*)(h + row * 1024 + tid * 4) = o;
}

// ---------------- stage C: batched reductions (3 barriered passes) ----------------
__global__ __launch_bounds__(256) void k_stage_c(
    const __bf16* __restrict__ outb, const float* __restrict__ ln_g,
    const float* __restrict__ ln_b, const float* __restrict__ phases,
    const float* __restrict__ temp, float* __restrict__ msq,
    __bf16* __restrict__ mag0, int b0) {
  __shared__ float scr[28];
  const int t = threadIdx.x;
  const long b = blockIdx.x;

  float xa[3][4], xb[3][4];
  float red[6];
#pragma unroll
  for (int s = 0; s < 3; ++s) {
    const __bf16* src = outb + b * 6144 + s * 2048;
    const bf16x4 va = *(const bf16x4*)(src + t * 4);
    const bf16x4 vb = *(const bf16x4*)(src + 1024 + t * 4);
    float sum = 0.f, ssq = 0.f;
#pragma unroll
    for (int j = 0; j < 4; ++j) {
      xa[s][j] = (float)va[j];
      xb[s][j] = (float)vb[j];
      sum += xa[s][j] + xb[s][j];
      ssq += xa[s][j] * xa[s][j] + xb[s][j] * xb[s][j];
    }
    red[2 * s] = sum;
    red[2 * s + 1] = ssq;
  }
  block_sumN<6>(red, scr);

  float ag[3][4], bg[3][4];
  float nsq[3];
#pragma unroll
  for (int s = 0; s < 3; ++s) {
    const float mu = red[2 * s] * (1.f / 2048.f);
    const float var = red[2 * s + 1] * (1.f / 2048.f) - mu * mu;
    const float rstd = rsqrtf(var + 1e-5f);
    const f32x4 ga = *(const f32x4*)(ln_g + s * 2048 + t * 4);
    const f32x4 ba = *(const f32x4*)(ln_b + s * 2048 + t * 4);
    const f32x4 gb = *(const f32x4*)(ln_g + s * 2048 + 1024 + t * 4);
    const f32x4 bb = *(const f32x4*)(ln_b + s * 2048 + 1024 + t * 4);
    float acc = 0.f;
#pragma unroll
    for (int j = 0; j < 4; ++j) {
      const float ya = (xa[s][j] - mu) * rstd * ga[j] + ba[j];
      const float yb = (xb[s][j] - mu) * rstd * gb[j] + bb[j];
      ag[s][j] = __expf(-ya * ya);
      bg[s][j] = __expf(-yb * yb);
      acc += ag[s][j] * ag[s][j] + bg[s][j] * bg[s][j];
    }
    nsq[s] = acc;
  }
  block_sumN<3>(nsq, scr);

  float wr[3][4], wi[3][4];
#pragma unroll
  for (int s = 0; s < 3; ++s) {
    const float factor = sqrtf(2.25f / (nsq[s] + 1e-8f));
    const float ph = phases[s];
    const float cs = __cosf(ph), sn = __sinf(ph);
#pragma unroll
    for (int j = 0; j < 4; ++j) {
      const float a = ag[s][j] * factor;
      const float b2 = bg[s][j] * factor;
      wr[s][j] = a * cs - b2 * sn;
      wi[s][j] = a * sn + b2 * cs;
    }
  }

  float mr[4];
  float dw[7] = {0.f, 0.f, 0.f, 0.f, 0.f, 0.f, 0.f};
#pragma unroll
  for (int j = 0; j < 4; ++j) {
    const float m = (wr[0][j] + wr[1][j] + wr[2][j]) * (1.f / 3.f);
    mr[j] = m;
    dw[6] += m * m;
    dw[0] += wr[0][j] * mr[j]; dw[1] += wr[0][j] * wr[0][j];
    dw[2] += wr[1][j] * mr[j]; dw[3] += wr[1][j] * wr[1][j];
    dw[4] += wr[2][j] * mr[j]; dw[5] += wr[2][j] * wr[2][j];
  }
  block_sumN<7>(dw, scr);
  const float mnorm = sqrtf(dw[6]) + 1e-8f;
  const float T = temp[0];
  const float c0 = dw[0] / ((sqrtf(dw[1]) + 1e-8f) * mnorm) / T;
  const float c1 = dw[2] / ((sqrtf(dw[3]) + 1e-8f) * mnorm) / T;
  const float c2 = dw[4] / ((sqrtf(dw[5]) + 1e-8f) * mnorm) / T;
  const float mx = fmaxf(c0, fmaxf(c1, c2));
  const float e0 = __expf(c0 - mx), e1 = __expf(c1 - mx), e2 = __expf(c2 - mx);
  const float inv = 1.f / (e0 + e1 + e2);
  const float w0 = e0 * inv, w1 = e1 * inv, w2 = e2 * inv;

  const long base = (long)(b0 + b) * 1024 + t * 4;
  f32x4 m2o;
  bf16x4 mgo;
#pragma unroll
  for (int j = 0; j < 4; ++j) {
    const float sr = wr[0][j] * w0 + wr[1][j] * w1 + wr[2][j] * w2;
    const float si = wi[0][j] * w0 + wi[1][j] * w1 + wi[2][j] * w2;
    const float m2 = sr * sr + si * si;
    m2o[j] = m2;
    mgo[j] = (__bf16)sqrtf(m2 + 1e-8f);
  }
  *(f32x4*)(msq + base) = m2o;
  *(bf16x4*)(mag0 + base) = mgo;
}

// ---------------- fused top-8 (u64-key over msq) + sparse cls1 ----------------
__global__ __launch_bounds__(256) void k_topk_cls1(
    const float* __restrict__ msq,
    const float* __restrict__ w1t, const float* __restrict__ b1,
    __bf16* __restrict__ hid) {
  __shared__ u64 candk[32];
  __shared__ u64 selk_s[8];
  __shared__ float ssum_s;
  const int tid = threadIdx.x;
  const int lane = tid & 63;
  const int wv = tid >> 6;
  const long b = blockIdx.x;

  f32x4 mv = *(const f32x4*)(msq + b * 1024 + tid * 4);
  u64 key[4];
#pragma unroll
  for (int j = 0; j < 4; ++j)
    key[j] = ((u64)__float_as_uint(mv[j]) << 32) | (unsigned)(~(unsigned)(tid * 4 + j));
  u64 lm = key[0];
  int jm = 0;
#pragma unroll
  for (int j = 1; j < 4; ++j)
    if (key[j] > lm) { lm = key[j]; jm = j; }

#pragma unroll 1
  for (int it = 0; it < 8; ++it) {
    u64 bk = lm;
#pragma unroll
    for (int m = 1; m < 64; m <<= 1) {
      const u64 ok = __shfl_xor(bk, m, 64);
      bk = ok > bk ? ok : bk;
    }
    if (lane == 0) candk[wv * 8 + it] = bk;
    if (bk == lm) {
      key[jm] = 0ULL;
      lm = key[0]; jm = 0;
#pragma unroll
      for (int j = 1; j < 4; ++j)
        if (key[j] > lm) { lm = key[j]; jm = j; }
    }
  }
  __syncthreads();

  if (wv == 0) {
    u64 ck = (lane < 32) ? candk[lane] : 0ULL;
    float ss = 0.f;
#pragma unroll 1
    for (int it = 0; it < 8; ++it) {
      u64 bk = ck;
#pragma unroll
      for (int m = 1; m < 64; m <<= 1) {
        const u64 ok = __shfl_xor(bk, m, 64);
        bk = ok > bk ? ok : bk;
      }
      if (ck == bk) ck = 0ULL;
      if (lane == 0) {
        selk_s[it] = bk;
        ss += __uint_as_float((unsigned)(bk >> 32));
      }
    }
    if (lane == 0) ssum_s = ss;
  }
  __syncthreads();

  const float denom = 1.f / (ssum_s + 1e-8f);
  float p[8];
  int idx[8];
#pragma unroll
  for (int k = 0; k < 8; ++k) {
    const u64 kk = selk_s[k];
    p[k] = __uint_as_float((unsigned)(kk >> 32)) * denom;
    idx[k] = (int)(~(unsigned)kk & 1023u);
  }

  const int o0 = tid * 4;
  float acc0 = b1[o0], acc1 = b1[o0 + 1], acc2 = b1[o0 + 2], acc3 = b1[o0 + 3];
#pragma unroll
  for (int k = 0; k < 8; ++k) {
    const f32x4 wrow = *(const f32x4*)(w1t + (long)idx[k] * 1024 + o0);
    acc0 += p[k] * wrow[0];
    acc1 += p[k] * wrow[1];
    acc2 += p[k] * wrow[2];
    acc3 += p[k] * wrow[3];
  }
  bf16x4 o = {(__bf16)gelu_fast(acc0), (__bf16)gelu_fast(acc1),
              (__bf16)gelu_fast(acc2), (__bf16)gelu_fast(acc3)};
  *(bf16x4*)(hid + b * 1024 + o0) = o;
}

extern "C" void kernel_launch(void* const* d_in, const int* in_sizes, int n_in,
                              void* d_out, int out_size, void* d_ws, size_t ws_size,
                              hipStream_t stream) {
  const float* x      = (const float*)d_in[0];
  const float* proj_w = (const float*)d_in[1];
  const float* proj_b = (const float*)d_in[2];
  const float* ln_p_g = (const float*)d_in[3];
  const float* ln_p_b = (const float*)d_in[4];
  const float* wf_w   = (const float*)d_in[5];
  const float* wf_b   = (const float*)d_in[6];
  const float* ln_g   = (const float*)d_in[7];
  const float* ln_b   = (const float*)d_in[8];
  const float* temperature = (const float*)d_in[9];
  const float* phases = (const float*)d_in[10];
  const float* gate_w = (const float*)d_in[11];
  const float* gate_b = (const float*)d_in[12];
  const float* cls_w1 = (const float*)d_in[13];
  const float* cls_b1 = (const float*)d_in[14];
  const float* cls_w2 = (const float*)d_in[15];
  const float* cls_b2 = (const float*)d_in[16];
  float* out = (float*)d_out;
  (void)in_sizes; (void)n_in; (void)out_size;

  char* ws = (char*)d_ws;
  const size_t MB = 1024 * 1024;

  if (ws_size >= 196 * MB) {
    // ---- full layout (196MB); xb eliminated (fused cast in G1) ----
    float*  msq  = (float*)(ws + 0);
    float*  y1   = (float*)(ws + 32 * MB);
    __bf16* mag0 = (__bf16*)(ws + 32 * MB);
    __bf16* mag1 = (__bf16*)(ws + 48 * MB);
    __bf16* outb = (__bf16*)(ws + 64 * MB);
    __bf16* hid  = (__bf16*)(ws + 64 * MB);
    float*  w1t  = (float*)(ws + 96 * MB);
    __bf16* hb   = (__bf16*)(ws + 160 * MB);
    __bf16* wfwb = (__bf16*)(ws + 176 * MB);
    __bf16* gwb  = (__bf16*)(ws + 188 * MB);
    __bf16* c2b  = (__bf16*)(ws + 190 * MB);
    __bf16* w1b  = (__bf16*)(ws + 192 * MB);

    k_cast_weights<<<9216, 256, 0, stream>>>(proj_w, w1b, wf_w, wfwb, gate_w, gwb);
    k_cast_pad<<<1024, 256, 0, stream>>>(cls_w2, c2b, 1000, 1024);

    // G1: fused f32->bf16 A staging (reads x directly)
    k_gemm_bt<0, 64, 1><<<dim3(8, 128), 256, 0, stream>>>(x, w1b, proj_b, y1, 8192, 1024, 2048, 1024, nullptr, nullptr);
    k_ln_gelu<<<8192, 256, 0, stream>>>(y1, ln_p_g, ln_p_b, hb);

    k_gemm256_bt<<<dim3(24, 32), 512, 0, stream>>>(hb, wfwb, wf_b, outb, 8192, 6144, 1024);
    k_stage_c<<<8192, 256, 0, stream>>>(outb, ln_g, ln_b, phases, temperature, msq, mag0, 0);

    k_transpose1k<<<dim3(32, 32), 256, 0, stream>>>(cls_w1, w1t);
    k_gemm_bt<6, 64><<<dim3(8, 128), 256, 0, stream>>>(mag0, gwb, gate_b, nullptr, 8192, 1024, 1024, 1024, msq, mag1);
    k_gemm_bt<7, 64><<<dim3(8, 128), 256, 0, stream>>>(mag1, gwb, gate_b, nullptr, 8192, 1024, 1024, 1024, msq, nullptr);

    k_topk_cls1<<<8192, 256, 0, stream>>>(msq, w1t, cls_b1, hid);
    k_gemm_bt<0, 64><<<dim3(8, 128), 256, 0, stream>>>(hid, c2b, cls_b2, out, 8192, 1024, 1024, 1000, nullptr, nullptr);
  } else {
    // ---- fallback layout (128MB): 4-chunk G2 path; xb eliminated ----
    float*  msq  = (float*)(ws + 0);
    float*  y1   = (float*)(ws + 32 * MB);
    __bf16* outc = (__bf16*)(ws + 32 * MB);
    __bf16* mag1 = (__bf16*)(ws + 32 * MB);
    __bf16* hid  = (__bf16*)(ws + 48 * MB);
    __bf16* w1b  = (__bf16*)(ws + 64 * MB);
    __bf16* mag0 = (__bf16*)(ws + 64 * MB);
    __bf16* wfwb = (__bf16*)(ws + 96 * MB);
    __bf16* hb   = (__bf16*)(ws + 108 * MB);
    float*  w1t  = (float*)(ws + 108 * MB);
    __bf16* gwb  = (__bf16*)(ws + 124 * MB);
    __bf16* c2b  = (__bf16*)(ws + 126 * MB);

    k_cast_weights<<<9216, 256, 0, stream>>>(proj_w, w1b, wf_w, wfwb, gate_w, gwb);
    k_cast_pad<<<1024, 256, 0, stream>>>(cls_w2, c2b, 1000, 1024);

    k_gemm_bt<0, 64, 1><<<dim3(8, 128), 256, 0, stream>>>(x, w1b, proj_b, y1, 8192, 1024, 2048, 1024, nullptr, nullptr);
    k_ln_gelu<<<8192, 256, 0, stream>>>(y1, ln_p_g, ln_p_b, hb);

    for (int c = 0; c < 4; ++c) {
      k_gemm_bt<1, 128><<<dim3(48, 16), 256, 0, stream>>>(hb + (size_t)c * 2048 * 1024, wfwb, wf_b,
                                                          outc, 2048, 6144, 1024, 6144, nullptr, nullptr);
      k_stage_c<<<2048, 256, 0, stream>>>(outc, ln_g, ln_b, phases, temperature,
                                          msq, mag0, c * 2048);
    }

    k_transpose1k<<<dim3(32, 32), 256, 0, stream>>>(cls_w1, w1t);
    k_gemm_bt<6, 64><<<dim3(8, 128), 256, 0, stream>>>(mag0, gwb, gate_b, nullptr, 8192, 1024, 1024, 1024, msq, mag1);
    k_gemm_bt<7, 64><<<dim3(8, 128), 256, 0, stream>>>(mag1, gwb, gate_b, nullptr, 8192, 1024, 1024, 1024, msq, nullptr);

    k_topk_cls1<<<8192, 256, 0, stream>>>(msq, w1t, cls_b1, hid);
    k_gemm_bt<0, 64><<<dim3(8, 128), 256, 0, stream>>>(hid, c2b, cls_b2, out, 8192, 1024, 1024, 1000, nullptr, nullptr);
  }
}

// Round 19
// 450.759 us; speedup vs baseline: 1.0426x; 1.0426x over previous
//
#include <hip/hip_runtime.h>
#include <cstdint>

typedef __attribute__((ext_vector_type(8))) __bf16 bf16x8;
typedef __attribute__((ext_vector_type(4))) __bf16 bf16x4;
typedef __attribute__((ext_vector_type(4))) float f32x4;
typedef unsigned long long u64;

__device__ __forceinline__ void gld_lds16(const void* g, void* l) {
  __builtin_amdgcn_global_load_lds(
      (const __attribute__((address_space(1))) void*)g,
      (__attribute__((address_space(3))) void*)l, 16, 0, 0);
}

__device__ __forceinline__ float block_sum(float v, float* scr) {
#pragma unroll
  for (int off = 32; off > 0; off >>= 1) v += __shfl_down(v, off, 64);
  const int w = threadIdx.x >> 6;
  __syncthreads();
  if ((threadIdx.x & 63) == 0) scr[w] = v;
  __syncthreads();
  float s = 0.f;
  const int nw = blockDim.x >> 6;
  for (int i = 0; i < nw; ++i) s += scr[i];
  return s;
}

// fused N-value block reduction (256 threads = 4 waves), scr size >= 4*N
template <int N>
__device__ __forceinline__ void block_sumN(float* v, float* scr) {
#pragma unroll
  for (int i = 0; i < N; ++i)
#pragma unroll
    for (int m = 1; m < 64; m <<= 1) v[i] += __shfl_xor(v[i], m, 64);
  const int w = threadIdx.x >> 6;
  __syncthreads();
  if ((threadIdx.x & 63) == 0)
#pragma unroll
    for (int i = 0; i < N; ++i) scr[w * N + i] = v[i];
  __syncthreads();
#pragma unroll
  for (int i = 0; i < N; ++i) {
    float s = 0.f;
    for (int ww = 0; ww < 4; ++ww) s += scr[ww * N + i];
    v[i] = s;
  }
}

// fast gelu: A&S 7.1.26 erf (|err|<1.5e-7) + hw exp
__device__ __forceinline__ float gelu_fast(float x) {
  const float ax = fabsf(x) * 0.70710678118654752f;
  const float t = 1.f / (1.f + 0.3275911f * ax);
  const float e = __expf(-ax * ax);
  float poly = 1.061405429f;
  poly = poly * t - 1.453152027f;
  poly = poly * t + 1.421413741f;
  poly = poly * t - 0.284496736f;
  poly = poly * t + 0.254829592f;
  const float erfax = 1.f - poly * t * e;
  const float er = copysignf(erfax, x);
  return 0.5f * x * (1.f + er);
}

// ---------------- x cast ----------------
__global__ __launch_bounds__(256) void k_cast_bf16(const float* __restrict__ in,
                                                   __bf16* __restrict__ out) {
  const long i = ((long)blockIdx.x * 256 + threadIdx.x) * 4;
  f32x4 v = *(const f32x4*)(in + i);
  bf16x4 o = {(__bf16)v[0], (__bf16)v[1], (__bf16)v[2], (__bf16)v[3]};
  *(bf16x4*)(out + i) = o;
}

// combined weight casts: proj_w(2048) | wf_w(6144) | gate_w(1024) | cls_w2 pad(1024)
__global__ __launch_bounds__(256) void k_cast_weights(
    const float* __restrict__ pw, __bf16* __restrict__ w1b,
    const float* __restrict__ wfw, __bf16* __restrict__ wfwb,
    const float* __restrict__ gw, __bf16* __restrict__ gwb,
    const float* __restrict__ c2, __bf16* __restrict__ c2b) {
  const int bid = blockIdx.x;
  if (bid >= 9216) {
    // cls_w2: 1000x1024 -> 1024x1024 zero-padded
    const long i = ((long)(bid - 9216) * 256 + threadIdx.x) * 4;
    const int row = (int)(i >> 10);
    const int col = (int)(i & 1023);
    bf16x4 o;
    if (row < 1000) {
      f32x4 v = *(const f32x4*)(c2 + (long)row * 1024 + col);
      o = (bf16x4){(__bf16)v[0], (__bf16)v[1], (__bf16)v[2], (__bf16)v[3]};
    } else {
      o = (bf16x4){(__bf16)0.f, (__bf16)0.f, (__bf16)0.f, (__bf16)0.f};
    }
    *(bf16x4*)(c2b + i) = o;
    return;
  }
  const float* in;
  __bf16* out;
  long base;
  if (bid < 2048) { in = pw; out = w1b; base = (long)bid * 1024; }
  else if (bid < 8192) { in = wfw; out = wfwb; base = (long)(bid - 2048) * 1024; }
  else { in = gw; out = gwb; base = (long)(bid - 8192) * 1024; }
  const long i = base + threadIdx.x * 4;
  f32x4 v = *(const f32x4*)(in + i);
  bf16x4 o = {(__bf16)v[0], (__bf16)v[1], (__bf16)v[2], (__bf16)v[3]};
  *(bf16x4*)(out + i) = o;
}

// ---------------- transpose 1024x1024 f32 ----------------
__global__ __launch_bounds__(256) void k_transpose1k(const float* __restrict__ in,
                                                     float* __restrict__ out) {
  __shared__ float t[32][33];
  const int tx = threadIdx.x & 31;
  const int ty = threadIdx.x >> 5;
  const int r0 = blockIdx.y * 32, c0 = blockIdx.x * 32;
#pragma unroll
  for (int k = 0; k < 4; ++k)
    t[ty + 8 * k][tx] = in[(long)(r0 + ty + 8 * k) * 1024 + c0 + tx];
  __syncthreads();
#pragma unroll
  for (int k = 0; k < 4; ++k)
    out[(long)(c0 + ty + 8 * k) * 1024 + r0 + tx] = t[tx][ty + 8 * k];
}

// ============ 256x256 8-wave BK=64 GEMM (R14/R17 proven) ============
__global__ __launch_bounds__(512, 1) void k_gemm256_bt(
    const __bf16* __restrict__ A, const __bf16* __restrict__ B,
    const float* __restrict__ bias, __bf16* __restrict__ C,
    int M, int N, int K) {
  __shared__ __align__(16) __bf16 lds[2][2][256 * 64];  // [slot][mat][row*64+k]
  const int tid = threadIdx.x;
  const int lane = tid & 63;
  const int wid = tid >> 6;
  const int wr = wid >> 2;
  const int wc = wid & 3;
  const int gx = gridDim.x, gy = gridDim.y;
  const int lin = blockIdx.y * gx + blockIdx.x;
  const int xcd = lin & 7;
  const int local = lin >> 3;
  const int byq = gy >> 3;
  const int bx = local / byq;
  const int by = xcd * byq + (local % byq);
  const int m0 = by * 256, n0 = bx * 256;
  const int fr = lane & 15;
  const int fx = lane >> 4;
  const int px = lane & 7;

  const __bf16* Abase = A + (long)m0 * K;
  const __bf16* Bbase = B + (long)n0 * K;

  auto stage_q = [&](int slot, int kt, int mat, int half) {
    const __bf16* src = (mat ? Bbase : Abase) + kt * 64;
#pragma unroll
    for (int q = 0; q < 2; ++q) {
      const int idx = q * 512 + tid;
      const int r = idx >> 3;
      const int pblk = idx & 7;
      const int row = half * 128 + r;
      const int lblk = pblk ^ (r & 7);
      gld_lds16(src + (long)row * K + lblk * 8,
                (char*)&lds[slot][mat][row * 64 + pblk * 8]);
    }
  };
  auto frag = [&](int slot, int mat, int row, int ks) -> bf16x8 {
    return *(const bf16x8*)&lds[slot][mat][row * 64 + ((((ks << 2) + fx) ^ px) << 3)];
  };

  f32x4 acc[8][4] = {};
  const int nt = K >> 6;
#pragma unroll
  for (int qp = 0; qp < 4; ++qp) stage_q(0, 0, qp >> 1, qp & 1);

  const int arow = wr * 128 + fr;
  const int brow = wc * 64 + fr;

  for (int t = 0; t < nt; ++t) {
    const int sc = t & 1, sn = sc ^ 1;
    if (t + 1 < nt) {
#pragma unroll
      for (int qp = 0; qp < 4; ++qp) stage_q(sn, t + 1, qp >> 1, qp & 1);
      asm volatile("s_waitcnt vmcnt(8)" ::: "memory");
    } else {
      asm volatile("s_waitcnt vmcnt(0)" ::: "memory");
    }
    __builtin_amdgcn_sched_barrier(0);
    __builtin_amdgcn_s_barrier();
    bf16x8 b0[4], b1[4];
#pragma unroll
    for (int j = 0; j < 4; ++j) {
      b0[j] = frag(sc, 1, brow + j * 16, 0);
      b1[j] = frag(sc, 1, brow + j * 16, 1);
    }
    __builtin_amdgcn_s_setprio(1);
#pragma unroll
    for (int im = 0; im < 8; ++im) {
      bf16x8 x0 = frag(sc, 0, arow + im * 16, 0);
      bf16x8 x1 = frag(sc, 0, arow + im * 16, 1);
#pragma unroll
      for (int j = 0; j < 4; ++j) {
        acc[im][j] = __builtin_amdgcn_mfma_f32_16x16x32_bf16(x0, b0[j], acc[im][j], 0, 0, 0);
        acc[im][j] = __builtin_amdgcn_mfma_f32_16x16x32_bf16(x1, b1[j], acc[im][j], 0, 0, 0);
      }
    }
    __builtin_amdgcn_s_setprio(0);
    __builtin_amdgcn_s_barrier();
  }

  // ---- epilogue: bounce C tile through dead staging LDS ----
  __bf16* cb = (__bf16*)&lds[0][0][0];
  const int lm0 = wr * 128 + fx * 4;
  const int lc0 = wc * 64 + fr;
#pragma unroll
  for (int j = 0; j < 4; ++j) {
    const float bv = bias[n0 + lc0 + j * 16];
#pragma unroll
    for (int im = 0; im < 8; ++im)
#pragma unroll
      for (int r = 0; r < 4; ++r)
        cb[(lm0 + im * 16 + r) * 256 + lc0 + j * 16] = (__bf16)(acc[im][j][r] + bv);
  }
  __syncthreads();
#pragma unroll
  for (int q = 0; q < 16; ++q) {
    const int idx = q * 512 + tid;
    const int row = idx >> 5;
    const int c8 = (idx & 31) * 8;
    *(f32x4*)(C + (long)(m0 + row) * N + n0 + c8) = *(const f32x4*)(cb + row * 256 + c8);
  }
}

// ---------------- GEMM: C = A @ B^T + bias (128-col tiles) ----------------
// EPI: 0 f32 store (LDS-bounce full-line), 1 bf16 store (scatter; fallback),
//      6 gate1: msq *= f^2 streaming + mag bf16 out, 7 gate2: msq *= f^2 streaming
template <int EPI, int BM>
__global__ __launch_bounds__(256) void k_gemm_bt(
    const __bf16* __restrict__ A, const __bf16* __restrict__ B,
    const float* __restrict__ bias, void* __restrict__ Cout,
    int M, int N, int K, int Nreal,
    float* __restrict__ msq, __bf16* __restrict__ magOut) {
  constexpr int MR = BM / 32;
  constexpr int STAGE_B = (2 * BM * 32 + 2 * 128 * 32) * 2;
  constexpr int CB_B = BM * 64 * 4;
  constexpr int SMEM_B = STAGE_B > CB_B ? STAGE_B : CB_B;
  __shared__ __align__(16) char smem[SMEM_B];
  __bf16* As = (__bf16*)smem;
  __bf16* Bs = (__bf16*)(smem + (size_t)2 * BM * 32 * 2);
  float* cb = (float*)smem;  // bounce region (BM x 64 f32)
  const int tid = threadIdx.x;
  const int lane = tid & 63;
  const int wid = tid >> 6;
  const int wr = wid >> 1, wc = wid & 1;

  const int gx = gridDim.x, gy = gridDim.y;
  const int nwg = gx * gy;
  int bx, by;
  if ((nwg & 7) == 0) {
    const int lin = blockIdx.y * gx + blockIdx.x;
    const int cpx = nwg >> 3;
    const int w = (lin & 7) * cpx + (lin >> 3);
    bx = w / gy;
    by = w % gy;
  } else {
    bx = blockIdx.x;
    by = blockIdx.y;
  }
  const int m0 = by * BM;
  const int n0 = bx * 128;
  const int frow = lane & 15;
  const int fk = (lane >> 4) * 8;
  f32x4 acc[MR][4] = {};

  auto stage = [&](int buf, int k0) {
    const __bf16* Ab = A + (long)m0 * K + k0;
    const __bf16* Bb = B + (long)n0 * K + k0;
    __bf16* Asb = As + buf * BM * 32;
    __bf16* Bsb = Bs + buf * 128 * 32;
#pragma unroll
    for (int q = 0; q < BM / 64; ++q) {
      const int idx = q * 256 + tid;
      const int row = idx >> 2;
      const int col = (idx & 3) * 8;
      gld_lds16(Ab + (long)row * K + col, (char*)Asb + idx * 16);
    }
#pragma unroll
    for (int q = 0; q < 2; ++q) {
      const int idx = q * 256 + tid;
      const int row = idx >> 2;
      const int col = (idx & 3) * 8;
      gld_lds16(Bb + (long)row * K + col, (char*)Bsb + idx * 16);
    }
  };

  const int nt = K >> 5;
  int cur = 0;
  stage(0, 0);
  __syncthreads();
  for (int t = 0; t < nt; ++t) {
    if (t + 1 < nt) stage(cur ^ 1, (t + 1) << 5);
    bf16x8 af[MR], bfr[4];
#pragma unroll
    for (int i = 0; i < MR; ++i)
      af[i] = *(const bf16x8*)(As + cur * BM * 32 + (wr * (BM / 2) + i * 16 + frow) * 32 + fk);
#pragma unroll
    for (int i = 0; i < 4; ++i)
      bfr[i] = *(const bf16x8*)(Bs + cur * 128 * 32 + (wc * 64 + i * 16 + frow) * 32 + fk);
#pragma unroll
    for (int im = 0; im < MR; ++im)
#pragma unroll
      for (int in = 0; in < 4; ++in)
        acc[im][in] = __builtin_amdgcn_mfma_f32_16x16x32_bf16(af[im], bfr[in],
                                                              acc[im][in], 0, 0, 0);
    __syncthreads();
    cur ^= 1;
  }

  if (EPI == 0 || EPI == 6 || EPI == 7) {
#pragma unroll 1
    for (int h = 0; h < 2; ++h) {
      __syncthreads();
      if (wc == h) {
#pragma unroll
        for (int in = 0; in < 4; ++in) {
          const int col = n0 + h * 64 + in * 16 + frow;
          const float bv = (col < Nreal) ? bias[col] : 0.f;
          const int lcc = in * 16 + frow;
#pragma unroll
          for (int im = 0; im < MR; ++im)
#pragma unroll
            for (int r = 0; r < 4; ++r) {
              const float v = acc[im][in][r] + bv;
              float sv;
              if (EPI == 0) {
                sv = v;
              } else {
                const float f = 1.f / (1.f + __expf(-v)) + 0.1f;
                sv = f * f;
              }
              cb[(wr * (BM / 2) + (lane >> 4) * 4 + im * 16 + r) * 64 + lcc] = sv;
            }
        }
      }
      __syncthreads();
#pragma unroll
      for (int q = 0; q < BM / 16; ++q) {
        const int idx = q * 256 + tid;
        const int row = idx >> 4;
        const int c4 = (idx & 15) * 4;
        const int gc = n0 + h * 64 + c4;
        if (EPI == 0) {
          if (gc < Nreal)
            *(f32x4*)((float*)Cout + (long)(m0 + row) * Nreal + gc) =
                *(const f32x4*)(cb + row * 64 + c4);
        } else {
          const long gix = (long)(m0 + row) * Nreal + gc;
          f32x4 m = *(const f32x4*)(msq + gix);
          const f32x4 f2 = *(const f32x4*)(cb + row * 64 + c4);
          m[0] *= f2[0]; m[1] *= f2[1]; m[2] *= f2[2]; m[3] *= f2[3];
          *(f32x4*)(msq + gix) = m;
          if (EPI == 6) {
            bf16x4 mg = {(__bf16)sqrtf(m[0] + 1e-8f), (__bf16)sqrtf(m[1] + 1e-8f),
                         (__bf16)sqrtf(m[2] + 1e-8f), (__bf16)sqrtf(m[3] + 1e-8f)};
            *(bf16x4*)(magOut + gix) = mg;
          }
        }
      }
    }
  } else {
    const int crow0 = m0 + wr * (BM / 2) + (lane >> 4) * 4;
    const int ccol0 = n0 + wc * 64 + (lane & 15);
#pragma unroll
    for (int in = 0; in < 4; ++in) {
      const int col = ccol0 + in * 16;
      if (col >= Nreal) continue;
      const float bv = bias[col];
#pragma unroll
      for (int im = 0; im < MR; ++im) {
#pragma unroll
        for (int r = 0; r < 4; ++r) {
          const long row = crow0 + im * 16 + r;
          ((__bf16*)Cout)[row * Nreal + col] = (__bf16)(acc[im][in][r] + bv);
        }
      }
    }
  }
}

// ---------------- LN (over 1024) + gelu -> bf16 ----------------
__global__ __launch_bounds__(256) void k_ln_gelu(const float* __restrict__ y,
                                                 const float* __restrict__ g,
                                                 const float* __restrict__ b,
                                                 __bf16* __restrict__ h) {
  __shared__ float scr[8];
  const int tid = threadIdx.x;
  const long row = blockIdx.x;
  const float* yr = y + row * 1024;
  f32x4 v = *(const f32x4*)(yr + tid * 4);
  float ls = v[0] + v[1] + v[2] + v[3];
  const float mu = block_sum(ls, scr) * (1.f / 1024.f);
  float lss = 0.f;
#pragma unroll
  for (int j = 0; j < 4; ++j) {
    const float d = v[j] - mu;
    lss += d * d;
  }
  const float var = block_sum(lss, scr) * (1.f / 1024.f);
  const float rstd = rsqrtf(var + 1e-5f);
  bf16x4 o;
#pragma unroll
  for (int j = 0; j < 4; ++j) {
    const int c = tid * 4 + j;
    const float t = (v[j] - mu) * rstd * g[c] + b[c];
    o[j] = (__bf16)gelu_fast(t);
  }
  *(bf16x4*)(h + row * 1024 + tid * 4) = o;
}

// ---------------- stage C: batched reductions (3 barriered passes) ----------------
__global__ __launch_bounds__(256) void k_stage_c(
    const __bf16* __restrict__ outb, const float* __restrict__ ln_g,
    const float* __restrict__ ln_b, const float* __restrict__ phases,
    const float* __restrict__ temp, float* __restrict__ msq,
    __bf16* __restrict__ mag0, int b0) {
  __shared__ float scr[28];
  const int t = threadIdx.x;
  const long b = blockIdx.x;

  float xa[3][4], xb[3][4];
  float red[6];
#pragma unroll
  for (int s = 0; s < 3; ++s) {
    const __bf16* src = outb + b * 6144 + s * 2048;
    const bf16x4 va = *(const bf16x4*)(src + t * 4);
    const bf16x4 vb = *(const bf16x4*)(src + 1024 + t * 4);
    float sum = 0.f, ssq = 0.f;
#pragma unroll
    for (int j = 0; j < 4; ++j) {
      xa[s][j] = (float)va[j];
      xb[s][j] = (float)vb[j];
      sum += xa[s][j] + xb[s][j];
      ssq += xa[s][j] * xa[s][j] + xb[s][j] * xb[s][j];
    }
    red[2 * s] = sum;
    red[2 * s + 1] = ssq;
  }
  block_sumN<6>(red, scr);

  float ag[3][4], bg[3][4];
  float nsq[3];
#pragma unroll
  for (int s = 0; s < 3; ++s) {
    const float mu = red[2 * s] * (1.f / 2048.f);
    const float var = red[2 * s + 1] * (1.f / 2048.f) - mu * mu;
    const float rstd = rsqrtf(var + 1e-5f);
    const f32x4 ga = *(const f32x4*)(ln_g + s * 2048 + t * 4);
    const f32x4 ba = *(const f32x4*)(ln_b + s * 2048 + t * 4);
    const f32x4 gb = *(const f32x4*)(ln_g + s * 2048 + 1024 + t * 4);
    const f32x4 bb = *(const f32x4*)(ln_b + s * 2048 + 1024 + t * 4);
    float acc = 0.f;
#pragma unroll
    for (int j = 0; j < 4; ++j) {
      const float ya = (xa[s][j] - mu) * rstd * ga[j] + ba[j];
      const float yb = (xb[s][j] - mu) * rstd * gb[j] + bb[j];
      ag[s][j] = __expf(-ya * ya);
      bg[s][j] = __expf(-yb * yb);
      acc += ag[s][j] * ag[s][j] + bg[s][j] * bg[s][j];
    }
    nsq[s] = acc;
  }
  block_sumN<3>(nsq, scr);

  float wr[3][4], wi[3][4];
#pragma unroll
  for (int s = 0; s < 3; ++s) {
    const float factor = sqrtf(2.25f / (nsq[s] + 1e-8f));
    const float ph = phases[s];
    const float cs = __cosf(ph), sn = __sinf(ph);
#pragma unroll
    for (int j = 0; j < 4; ++j) {
      const float a = ag[s][j] * factor;
      const float b2 = bg[s][j] * factor;
      wr[s][j] = a * cs - b2 * sn;
      wi[s][j] = a * sn + b2 * cs;
    }
  }

  float mr[4];
  float dw[7] = {0.f, 0.f, 0.f, 0.f, 0.f, 0.f, 0.f};
#pragma unroll
  for (int j = 0; j < 4; ++j) {
    const float m = (wr[0][j] + wr[1][j] + wr[2][j]) * (1.f / 3.f);
    mr[j] = m;
    dw[6] += m * m;
    dw[0] += wr[0][j] * mr[j]; dw[1] += wr[0][j] * wr[0][j];
    dw[2] += wr[1][j] * mr[j]; dw[3] += wr[1][j] * wr[1][j];
    dw[4] += wr[2][j] * mr[j]; dw[5] += wr[2][j] * wr[2][j];
  }
  block_sumN<7>(dw, scr);
  const float mnorm = sqrtf(dw[6]) + 1e-8f;
  const float T = temp[0];
  const float c0 = dw[0] / ((sqrtf(dw[1]) + 1e-8f) * mnorm) / T;
  const float c1 = dw[2] / ((sqrtf(dw[3]) + 1e-8f) * mnorm) / T;
  const float c2 = dw[4] / ((sqrtf(dw[5]) + 1e-8f) * mnorm) / T;
  const float mx = fmaxf(c0, fmaxf(c1, c2));
  const float e0 = __expf(c0 - mx), e1 = __expf(c1 - mx), e2 = __expf(c2 - mx);
  const float inv = 1.f / (e0 + e1 + e2);
  const float w0 = e0 * inv, w1 = e1 * inv, w2 = e2 * inv;

  const long base = (long)(b0 + b) * 1024 + t * 4;
  f32x4 m2o;
  bf16x4 mgo;
#pragma unroll
  for (int j = 0; j < 4; ++j) {
    const float sr = wr[0][j] * w0 + wr[1][j] * w1 + wr[2][j] * w2;
    const float si = wi[0][j] * w0 + wi[1][j] * w1 + wi[2][j] * w2;
    const float m2 = sr * sr + si * si;
    m2o[j] = m2;
    mgo[j] = (__bf16)sqrtf(m2 + 1e-8f);
  }
  *(f32x4*)(msq + base) = m2o;
  *(bf16x4*)(mag0 + base) = mgo;
}

// ---------------- fused top-8 (u64-key over msq) + sparse cls1 ----------------
__global__ __launch_bounds__(256) void k_topk_cls1(
    const float* __restrict__ msq,
    const float* __restrict__ w1t, const float* __restrict__ b1,
    __bf16* __restrict__ hid) {
  __shared__ u64 candk[32];
  __shared__ u64 selk_s[8];
  __shared__ float ssum_s;
  const int tid = threadIdx.x;
  const int lane = tid & 63;
  const int wv = tid >> 6;
  const long b = blockIdx.x;

  f32x4 mv = *(const f32x4*)(msq + b * 1024 + tid * 4);
  u64 key[4];
#pragma unroll
  for (int j = 0; j < 4; ++j)
    key[j] = ((u64)__float_as_uint(mv[j]) << 32) | (unsigned)(~(unsigned)(tid * 4 + j));
  u64 lm = key[0];
  int jm = 0;
#pragma unroll
  for (int j = 1; j < 4; ++j)
    if (key[j] > lm) { lm = key[j]; jm = j; }

#pragma unroll 1
  for (int it = 0; it < 8; ++it) {
    u64 bk = lm;
#pragma unroll
    for (int m = 1; m < 64; m <<= 1) {
      const u64 ok = __shfl_xor(bk, m, 64);
      bk = ok > bk ? ok : bk;
    }
    if (lane == 0) candk[wv * 8 + it] = bk;
    if (bk == lm) {
      key[jm] = 0ULL;
      lm = key[0]; jm = 0;
#pragma unroll
      for (int j = 1; j < 4; ++j)
        if (key[j] > lm) { lm = key[j]; jm = j; }
    }
  }
  __syncthreads();

  if (wv == 0) {
    u64 ck = (lane < 32) ? candk[lane] : 0ULL;
    float ss = 0.f;
#pragma unroll 1
    for (int it = 0; it < 8; ++it) {
      u64 bk = ck;
#pragma unroll
      for (int m = 1; m < 64; m <<= 1) {
        const u64 ok = __shfl_xor(bk, m, 64);
        bk = ok > bk ? ok : bk;
      }
      if (ck == bk) ck = 0ULL;
      if (lane == 0) {
        selk_s[it] = bk;
        ss += __uint_as_float((unsigned)(bk >> 32));
      }
    }
    if (lane == 0) ssum_s = ss;
  }
  __syncthreads();

  const float denom = 1.f / (ssum_s + 1e-8f);
  float p[8];
  int idx[8];
#pragma unroll
  for (int k = 0; k < 8; ++k) {
    const u64 kk = selk_s[k];
    p[k] = __uint_as_float((unsigned)(kk >> 32)) * denom;
    idx[k] = (int)(~(unsigned)kk & 1023u);
  }

  const int o0 = tid * 4;
  float acc0 = b1[o0], acc1 = b1[o0 + 1], acc2 = b1[o0 + 2], acc3 = b1[o0 + 3];
#pragma unroll
  for (int k = 0; k < 8; ++k) {
    const f32x4 wrow = *(const f32x4*)(w1t + (long)idx[k] * 1024 + o0);
    acc0 += p[k] * wrow[0];
    acc1 += p[k] * wrow[1];
    acc2 += p[k] * wrow[2];
    acc3 += p[k] * wrow[3];
  }
  bf16x4 o = {(__bf16)gelu_fast(acc0), (__bf16)gelu_fast(acc1),
              (__bf16)gelu_fast(acc2), (__bf16)gelu_fast(acc3)};
  *(bf16x4*)(hid + b * 1024 + o0) = o;
}

extern "C" void kernel_launch(void* const* d_in, const int* in_sizes, int n_in,
                              void* d_out, int out_size, void* d_ws, size_t ws_size,
                              hipStream_t stream) {
  const float* x      = (const float*)d_in[0];
  const float* proj_w = (const float*)d_in[1];
  const float* proj_b = (const float*)d_in[2];
  const float* ln_p_g = (const float*)d_in[3];
  const float* ln_p_b = (const float*)d_in[4];
  const float* wf_w   = (const float*)d_in[5];
  const float* wf_b   = (const float*)d_in[6];
  const float* ln_g   = (const float*)d_in[7];
  const float* ln_b   = (const float*)d_in[8];
  const float* temperature = (const float*)d_in[9];
  const float* phases = (const float*)d_in[10];
  const float* gate_w = (const float*)d_in[11];
  const float* gate_b = (const float*)d_in[12];
  const float* cls_w1 = (const float*)d_in[13];
  const float* cls_b1 = (const float*)d_in[14];
  const float* cls_w2 = (const float*)d_in[15];
  const float* cls_b2 = (const float*)d_in[16];
  float* out = (float*)d_out;
  (void)in_sizes; (void)n_in; (void)out_size;

  char* ws = (char*)d_ws;
  const size_t MB = 1024 * 1024;

  if (ws_size >= 196 * MB) {
    // ---- full layout (196MB) ----
    __bf16* xb   = (__bf16*)(ws + 0);
    float*  msq  = (float*)(ws + 0);
    float*  y1   = (float*)(ws + 32 * MB);
    __bf16* mag0 = (__bf16*)(ws + 32 * MB);
    __bf16* mag1 = (__bf16*)(ws + 48 * MB);
    __bf16* outb = (__bf16*)(ws + 64 * MB);
    __bf16* hid  = (__bf16*)(ws + 64 * MB);
    float*  w1t  = (float*)(ws + 96 * MB);
    __bf16* hb   = (__bf16*)(ws + 160 * MB);
    __bf16* wfwb = (__bf16*)(ws + 176 * MB);
    __bf16* gwb  = (__bf16*)(ws + 188 * MB);
    __bf16* c2b  = (__bf16*)(ws + 190 * MB);
    __bf16* w1b  = (__bf16*)(ws + 192 * MB);

    k_cast_bf16<<<16384, 256, 0, stream>>>(x, xb);
    k_cast_weights<<<10240, 256, 0, stream>>>(proj_w, w1b, wf_w, wfwb, gate_w, gwb, cls_w2, c2b);

    k_gemm_bt<0, 64><<<dim3(8, 128), 256, 0, stream>>>(xb, w1b, proj_b, y1, 8192, 1024, 2048, 1024, nullptr, nullptr);
    k_ln_gelu<<<8192, 256, 0, stream>>>(y1, ln_p_g, ln_p_b, hb);

    k_gemm256_bt<<<dim3(24, 32), 512, 0, stream>>>(hb, wfwb, wf_b, outb, 8192, 6144, 1024);
    k_stage_c<<<8192, 256, 0, stream>>>(outb, ln_g, ln_b, phases, temperature, msq, mag0, 0);

    k_transpose1k<<<dim3(32, 32), 256, 0, stream>>>(cls_w1, w1t);
    k_gemm_bt<6, 64><<<dim3(8, 128), 256, 0, stream>>>(mag0, gwb, gate_b, nullptr, 8192, 1024, 1024, 1024, msq, mag1);
    k_gemm_bt<7, 64><<<dim3(8, 128), 256, 0, stream>>>(mag1, gwb, gate_b, nullptr, 8192, 1024, 1024, 1024, msq, nullptr);

    k_topk_cls1<<<8192, 256, 0, stream>>>(msq, w1t, cls_b1, hid);
    k_gemm_bt<0, 64><<<dim3(8, 128), 256, 0, stream>>>(hid, c2b, cls_b2, out, 8192, 1024, 1024, 1000, nullptr, nullptr);
  } else {
    // ---- fallback layout (128MB): 4-chunk G2 path ----
    __bf16* xb   = (__bf16*)(ws + 0);
    float*  msq  = (float*)(ws + 0);
    float*  y1   = (float*)(ws + 32 * MB);
    __bf16* outc = (__bf16*)(ws + 32 * MB);
    __bf16* mag1 = (__bf16*)(ws + 32 * MB);
    __bf16* hid  = (__bf16*)(ws + 48 * MB);
    __bf16* w1b  = (__bf16*)(ws + 64 * MB);
    __bf16* mag0 = (__bf16*)(ws + 64 * MB);
    __bf16* wfwb = (__bf16*)(ws + 96 * MB);
    __bf16* hb   = (__bf16*)(ws + 108 * MB);
    float*  w1t  = (float*)(ws + 108 * MB);
    __bf16* gwb  = (__bf16*)(ws + 124 * MB);
    __bf16* c2b  = (__bf16*)(ws + 126 * MB);

    k_cast_bf16<<<16384, 256, 0, stream>>>(x, xb);
    k_cast_weights<<<10240, 256, 0, stream>>>(proj_w, w1b, wf_w, wfwb, gate_w, gwb, cls_w2, c2b);

    k_gemm_bt<0, 64><<<dim3(8, 128), 256, 0, stream>>>(xb, w1b, proj_b, y1, 8192, 1024, 2048, 1024, nullptr, nullptr);
    k_ln_gelu<<<8192, 256, 0, stream>>>(y1, ln_p_g, ln_p_b, hb);

    for (int c = 0; c < 4; ++c) {
      k_gemm_bt<1, 128><<<dim3(48, 16), 256, 0, stream>>>(hb + (size_t)c * 2048 * 1024, wfwb, wf_b,
                                                          outc, 2048, 6144, 1024, 6144, nullptr, nullptr);
      k_stage_c<<<2048, 256, 0, stream>>>(outc, ln_g, ln_b, phases, temperature,
                                          msq, mag0, c * 2048);
    }

    k_transpose1k<<<dim3(32, 32), 256, 0, stream>>>(cls_w1, w1t);
    k_gemm_bt<6, 64><<<dim3(8, 128), 256, 0, stream>>>(mag0, gwb, gate_b, nullptr, 8192, 1024, 1024, 1024, msq, mag1);
    k_gemm_bt<7, 64><<<dim3(8, 128), 256, 0, stream>>>(mag1, gwb, gate_b, nullptr, 8192, 1024, 1024, 1024, msq, nullptr);

    k_topk_cls1<<<8192, 256, 0, stream>>>(msq, w1t, cls_b1, hid);
    k_gemm_bt<0, 64><<<dim3(8, 128), 256, 0, stream>>>(hid, c2b, cls_b2, out, 8192, 1024, 1024, 1000, nullptr, nullptr);
  }
}

// Round 20
// 436.232 us; speedup vs baseline: 1.0773x; 1.0333x over previous
//
#include <hip/hip_runtime.h>
#include <cstdint>

typedef __attribute__((ext_vector_type(8))) __bf16 bf16x8;
typedef __attribute__((ext_vector_type(4))) __bf16 bf16x4;
typedef __attribute__((ext_vector_type(4))) float f32x4;
typedef unsigned long long u64;

__device__ __forceinline__ void gld_lds16(const void* g, void* l) {
  __builtin_amdgcn_global_load_lds(
      (const __attribute__((address_space(1))) void*)g,
      (__attribute__((address_space(3))) void*)l, 16, 0, 0);
}

__device__ __forceinline__ float block_sum(float v, float* scr) {
#pragma unroll
  for (int off = 32; off > 0; off >>= 1) v += __shfl_down(v, off, 64);
  const int w = threadIdx.x >> 6;
  __syncthreads();
  if ((threadIdx.x & 63) == 0) scr[w] = v;
  __syncthreads();
  float s = 0.f;
  const int nw = blockDim.x >> 6;
  for (int i = 0; i < nw; ++i) s += scr[i];
  return s;
}

// fused N-value block reduction (256 threads = 4 waves), scr size >= 4*N
template <int N>
__device__ __forceinline__ void block_sumN(float* v, float* scr) {
#pragma unroll
  for (int i = 0; i < N; ++i)
#pragma unroll
    for (int m = 1; m < 64; m <<= 1) v[i] += __shfl_xor(v[i], m, 64);
  const int w = threadIdx.x >> 6;
  __syncthreads();
  if ((threadIdx.x & 63) == 0)
#pragma unroll
    for (int i = 0; i < N; ++i) scr[w * N + i] = v[i];
  __syncthreads();
#pragma unroll
  for (int i = 0; i < N; ++i) {
    float s = 0.f;
    for (int ww = 0; ww < 4; ++ww) s += scr[ww * N + i];
    v[i] = s;
  }
}

// fast gelu: A&S 7.1.26 erf (|err|<1.5e-7) + hw exp
__device__ __forceinline__ float gelu_fast(float x) {
  const float ax = fabsf(x) * 0.70710678118654752f;
  const float t = 1.f / (1.f + 0.3275911f * ax);
  const float e = __expf(-ax * ax);
  float poly = 1.061405429f;
  poly = poly * t - 1.453152027f;
  poly = poly * t + 1.421413741f;
  poly = poly * t - 0.284496736f;
  poly = poly * t + 0.254829592f;
  const float erfax = 1.f - poly * t * e;
  const float er = copysignf(erfax, x);
  return 0.5f * x * (1.f + er);
}

// ---------------- x cast ----------------
__global__ __launch_bounds__(256) void k_cast_bf16(const float* __restrict__ in,
                                                   __bf16* __restrict__ out) {
  const long i = ((long)blockIdx.x * 256 + threadIdx.x) * 4;
  f32x4 v = *(const f32x4*)(in + i);
  bf16x4 o = {(__bf16)v[0], (__bf16)v[1], (__bf16)v[2], (__bf16)v[3]};
  *(bf16x4*)(out + i) = o;
}

// combined weight casts: proj_w(2048) | wf_w(6144) | gate_w(1024) | cls_w2 pad(1024)
__global__ __launch_bounds__(256) void k_cast_weights(
    const float* __restrict__ pw, __bf16* __restrict__ w1b,
    const float* __restrict__ wfw, __bf16* __restrict__ wfwb,
    const float* __restrict__ gw, __bf16* __restrict__ gwb,
    const float* __restrict__ c2, __bf16* __restrict__ c2b) {
  const int bid = blockIdx.x;
  if (bid >= 9216) {
    const long i = ((long)(bid - 9216) * 256 + threadIdx.x) * 4;
    const int row = (int)(i >> 10);
    const int col = (int)(i & 1023);
    bf16x4 o;
    if (row < 1000) {
      f32x4 v = *(const f32x4*)(c2 + (long)row * 1024 + col);
      o = (bf16x4){(__bf16)v[0], (__bf16)v[1], (__bf16)v[2], (__bf16)v[3]};
    } else {
      o = (bf16x4){(__bf16)0.f, (__bf16)0.f, (__bf16)0.f, (__bf16)0.f};
    }
    *(bf16x4*)(c2b + i) = o;
    return;
  }
  const float* in;
  __bf16* out;
  long base;
  if (bid < 2048) { in = pw; out = w1b; base = (long)bid * 1024; }
  else if (bid < 8192) { in = wfw; out = wfwb; base = (long)(bid - 2048) * 1024; }
  else { in = gw; out = gwb; base = (long)(bid - 8192) * 1024; }
  const long i = base + threadIdx.x * 4;
  f32x4 v = *(const f32x4*)(in + i);
  bf16x4 o = {(__bf16)v[0], (__bf16)v[1], (__bf16)v[2], (__bf16)v[3]};
  *(bf16x4*)(out + i) = o;
}

// ---------------- transpose 1024x1024 f32 ----------------
__global__ __launch_bounds__(256) void k_transpose1k(const float* __restrict__ in,
                                                     float* __restrict__ out) {
  __shared__ float t[32][33];
  const int tx = threadIdx.x & 31;
  const int ty = threadIdx.x >> 5;
  const int r0 = blockIdx.y * 32, c0 = blockIdx.x * 32;
#pragma unroll
  for (int k = 0; k < 4; ++k)
    t[ty + 8 * k][tx] = in[(long)(r0 + ty + 8 * k) * 1024 + c0 + tx];
  __syncthreads();
#pragma unroll
  for (int k = 0; k < 4; ++k)
    out[(long)(c0 + ty + 8 * k) * 1024 + r0 + tx] = t[tx][ty + 8 * k];
}

// ============ 256x256 8-wave BK=64 GEMM (R14/R17 proven) ============
__global__ __launch_bounds__(512, 1) void k_gemm256_bt(
    const __bf16* __restrict__ A, const __bf16* __restrict__ B,
    const float* __restrict__ bias, __bf16* __restrict__ C,
    int M, int N, int K) {
  __shared__ __align__(16) __bf16 lds[2][2][256 * 64];  // [slot][mat][row*64+k]
  const int tid = threadIdx.x;
  const int lane = tid & 63;
  const int wid = tid >> 6;
  const int wr = wid >> 2;
  const int wc = wid & 3;
  const int gx = gridDim.x, gy = gridDim.y;
  const int lin = blockIdx.y * gx + blockIdx.x;
  const int xcd = lin & 7;
  const int local = lin >> 3;
  const int byq = gy >> 3;
  const int bx = local / byq;
  const int by = xcd * byq + (local % byq);
  const int m0 = by * 256, n0 = bx * 256;
  const int fr = lane & 15;
  const int fx = lane >> 4;
  const int px = lane & 7;

  const __bf16* Abase = A + (long)m0 * K;
  const __bf16* Bbase = B + (long)n0 * K;

  auto stage_q = [&](int slot, int kt, int mat, int half) {
    const __bf16* src = (mat ? Bbase : Abase) + kt * 64;
#pragma unroll
    for (int q = 0; q < 2; ++q) {
      const int idx = q * 512 + tid;
      const int r = idx >> 3;
      const int pblk = idx & 7;
      const int row = half * 128 + r;
      const int lblk = pblk ^ (r & 7);
      gld_lds16(src + (long)row * K + lblk * 8,
                (char*)&lds[slot][mat][row * 64 + pblk * 8]);
    }
  };
  auto frag = [&](int slot, int mat, int row, int ks) -> bf16x8 {
    return *(const bf16x8*)&lds[slot][mat][row * 64 + ((((ks << 2) + fx) ^ px) << 3)];
  };

  f32x4 acc[8][4] = {};
  const int nt = K >> 6;
#pragma unroll
  for (int qp = 0; qp < 4; ++qp) stage_q(0, 0, qp >> 1, qp & 1);

  const int arow = wr * 128 + fr;
  const int brow = wc * 64 + fr;

  for (int t = 0; t < nt; ++t) {
    const int sc = t & 1, sn = sc ^ 1;
    if (t + 1 < nt) {
#pragma unroll
      for (int qp = 0; qp < 4; ++qp) stage_q(sn, t + 1, qp >> 1, qp & 1);
      asm volatile("s_waitcnt vmcnt(8)" ::: "memory");
    } else {
      asm volatile("s_waitcnt vmcnt(0)" ::: "memory");
    }
    __builtin_amdgcn_sched_barrier(0);
    __builtin_amdgcn_s_barrier();
    bf16x8 b0[4], b1[4];
#pragma unroll
    for (int j = 0; j < 4; ++j) {
      b0[j] = frag(sc, 1, brow + j * 16, 0);
      b1[j] = frag(sc, 1, brow + j * 16, 1);
    }
    __builtin_amdgcn_s_setprio(1);
#pragma unroll
    for (int im = 0; im < 8; ++im) {
      bf16x8 x0 = frag(sc, 0, arow + im * 16, 0);
      bf16x8 x1 = frag(sc, 0, arow + im * 16, 1);
#pragma unroll
      for (int j = 0; j < 4; ++j) {
        acc[im][j] = __builtin_amdgcn_mfma_f32_16x16x32_bf16(x0, b0[j], acc[im][j], 0, 0, 0);
        acc[im][j] = __builtin_amdgcn_mfma_f32_16x16x32_bf16(x1, b1[j], acc[im][j], 0, 0, 0);
      }
    }
    __builtin_amdgcn_s_setprio(0);
    __builtin_amdgcn_s_barrier();
  }

  // ---- epilogue: bounce C tile through dead staging LDS ----
  __bf16* cb = (__bf16*)&lds[0][0][0];
  const int lm0 = wr * 128 + fx * 4;
  const int lc0 = wc * 64 + fr;
#pragma unroll
  for (int j = 0; j < 4; ++j) {
    const float bv = bias[n0 + lc0 + j * 16];
#pragma unroll
    for (int im = 0; im < 8; ++im)
#pragma unroll
      for (int r = 0; r < 4; ++r)
        cb[(lm0 + im * 16 + r) * 256 + lc0 + j * 16] = (__bf16)(acc[im][j][r] + bv);
  }
  __syncthreads();
#pragma unroll
  for (int q = 0; q < 16; ++q) {
    const int idx = q * 512 + tid;
    const int row = idx >> 5;
    const int c8 = (idx & 31) * 8;
    *(f32x4*)(C + (long)(m0 + row) * N + n0 + c8) = *(const f32x4*)(cb + row * 256 + c8);
  }
}

// ---------------- GEMM: C = A @ B^T + bias (128-col tiles) ----------------
// A-resident XCD partition when gy%8==0 (else legacy swizzle).
// EPI: 0 f32 store (LDS-bounce full-line), 1 bf16 store (scatter; fallback),
//      6 gate1: msq *= f^2 streaming + mag bf16 out, 7 gate2: msq *= f^2 streaming
template <int EPI, int BM>
__global__ __launch_bounds__(256) void k_gemm_bt(
    const __bf16* __restrict__ A, const __bf16* __restrict__ B,
    const float* __restrict__ bias, void* __restrict__ Cout,
    int M, int N, int K, int Nreal,
    float* __restrict__ msq, __bf16* __restrict__ magOut) {
  constexpr int MR = BM / 32;
  constexpr int STAGE_B = (2 * BM * 32 + 2 * 128 * 32) * 2;
  constexpr int CB_B = BM * 64 * 4;
  constexpr int SMEM_B = STAGE_B > CB_B ? STAGE_B : CB_B;
  __shared__ __align__(16) char smem[SMEM_B];
  __bf16* As = (__bf16*)smem;
  __bf16* Bs = (__bf16*)(smem + (size_t)2 * BM * 32 * 2);
  float* cb = (float*)smem;  // bounce region (BM x 64 f32)
  const int tid = threadIdx.x;
  const int lane = tid & 63;
  const int wid = tid >> 6;
  const int wr = wid >> 1, wc = wid & 1;

  const int gx = gridDim.x, gy = gridDim.y;
  const int nwg = gx * gy;
  int bx, by;
  if ((gy & 7) == 0) {
    // A-resident: each XCD owns gy/8 consecutive by panels, streams bx
    const int lin = blockIdx.y * gx + blockIdx.x;
    const int xcd = lin & 7;
    const int local = lin >> 3;
    const int byq = gy >> 3;
    bx = local / byq;
    by = xcd * byq + (local % byq);
  } else if ((nwg & 7) == 0) {
    const int lin = blockIdx.y * gx + blockIdx.x;
    const int cpx = nwg >> 3;
    const int w = (lin & 7) * cpx + (lin >> 3);
    bx = w / gy;
    by = w % gy;
  } else {
    bx = blockIdx.x;
    by = blockIdx.y;
  }
  const int m0 = by * BM;
  const int n0 = bx * 128;
  const int frow = lane & 15;
  const int fk = (lane >> 4) * 8;
  f32x4 acc[MR][4] = {};

  auto stage = [&](int buf, int k0) {
    const __bf16* Ab = A + (long)m0 * K + k0;
    const __bf16* Bb = B + (long)n0 * K + k0;
    __bf16* Asb = As + buf * BM * 32;
    __bf16* Bsb = Bs + buf * 128 * 32;
#pragma unroll
    for (int q = 0; q < BM / 64; ++q) {
      const int idx = q * 256 + tid;
      const int row = idx >> 2;
      const int col = (idx & 3) * 8;
      gld_lds16(Ab + (long)row * K + col, (char*)Asb + idx * 16);
    }
#pragma unroll
    for (int q = 0; q < 2; ++q) {
      const int idx = q * 256 + tid;
      const int row = idx >> 2;
      const int col = (idx & 3) * 8;
      gld_lds16(Bb + (long)row * K + col, (char*)Bsb + idx * 16);
    }
  };

  const int nt = K >> 5;
  int cur = 0;
  stage(0, 0);
  __syncthreads();
  for (int t = 0; t < nt; ++t) {
    if (t + 1 < nt) stage(cur ^ 1, (t + 1) << 5);
    bf16x8 af[MR], bfr[4];
#pragma unroll
    for (int i = 0; i < MR; ++i)
      af[i] = *(const bf16x8*)(As + cur * BM * 32 + (wr * (BM / 2) + i * 16 + frow) * 32 + fk);
#pragma unroll
    for (int i = 0; i < 4; ++i)
      bfr[i] = *(const bf16x8*)(Bs + cur * 128 * 32 + (wc * 64 + i * 16 + frow) * 32 + fk);
#pragma unroll
    for (int im = 0; im < MR; ++im)
#pragma unroll
      for (int in = 0; in < 4; ++in)
        acc[im][in] = __builtin_amdgcn_mfma_f32_16x16x32_bf16(af[im], bfr[in],
                                                              acc[im][in], 0, 0, 0);
    __syncthreads();
    cur ^= 1;
  }

  if (EPI == 0 || EPI == 6 || EPI == 7) {
#pragma unroll 1
    for (int h = 0; h < 2; ++h) {
      __syncthreads();
      if (wc == h) {
#pragma unroll
        for (int in = 0; in < 4; ++in) {
          const int col = n0 + h * 64 + in * 16 + frow;
          const float bv = (col < Nreal) ? bias[col] : 0.f;
          const int lcc = in * 16 + frow;
#pragma unroll
          for (int im = 0; im < MR; ++im)
#pragma unroll
            for (int r = 0; r < 4; ++r) {
              const float v = acc[im][in][r] + bv;
              float sv;
              if (EPI == 0) {
                sv = v;
              } else {
                const float f = 1.f / (1.f + __expf(-v)) + 0.1f;
                sv = f * f;
              }
              cb[(wr * (BM / 2) + (lane >> 4) * 4 + im * 16 + r) * 64 + lcc] = sv;
            }
        }
      }
      __syncthreads();
#pragma unroll
      for (int q = 0; q < BM / 16; ++q) {
        const int idx = q * 256 + tid;
        const int row = idx >> 4;
        const int c4 = (idx & 15) * 4;
        const int gc = n0 + h * 64 + c4;
        if (EPI == 0) {
          if (gc < Nreal)
            *(f32x4*)((float*)Cout + (long)(m0 + row) * Nreal + gc) =
                *(const f32x4*)(cb + row * 64 + c4);
        } else {
          const long gix = (long)(m0 + row) * Nreal + gc;
          f32x4 m = *(const f32x4*)(msq + gix);
          const f32x4 f2 = *(const f32x4*)(cb + row * 64 + c4);
          m[0] *= f2[0]; m[1] *= f2[1]; m[2] *= f2[2]; m[3] *= f2[3];
          *(f32x4*)(msq + gix) = m;
          if (EPI == 6) {
            bf16x4 mg = {(__bf16)sqrtf(m[0] + 1e-8f), (__bf16)sqrtf(m[1] + 1e-8f),
                         (__bf16)sqrtf(m[2] + 1e-8f), (__bf16)sqrtf(m[3] + 1e-8f)};
            *(bf16x4*)(magOut + gix) = mg;
          }
        }
      }
    }
  } else {
    const int crow0 = m0 + wr * (BM / 2) + (lane >> 4) * 4;
    const int ccol0 = n0 + wc * 64 + (lane & 15);
#pragma unroll
    for (int in = 0; in < 4; ++in) {
      const int col = ccol0 + in * 16;
      if (col >= Nreal) continue;
      const float bv = bias[col];
#pragma unroll
      for (int im = 0; im < MR; ++im) {
#pragma unroll
        for (int r = 0; r < 4; ++r) {
          const long row = crow0 + im * 16 + r;
          ((__bf16*)Cout)[row * Nreal + col] = (__bf16)(acc[im][in][r] + bv);
        }
      }
    }
  }
}

// ---------------- LN (over 1024) + gelu -> bf16 ----------------
__global__ __launch_bounds__(256) void k_ln_gelu(const float* __restrict__ y,
                                                 const float* __restrict__ g,
                                                 const float* __restrict__ b,
                                                 __bf16* __restrict__ h) {
  __shared__ float scr[8];
  const int tid = threadIdx.x;
  const long row = blockIdx.x;
  const float* yr = y + row * 1024;
  f32x4 v = *(const f32x4*)(yr + tid * 4);
  float ls = v[0] + v[1] + v[2] + v[3];
  const float mu = block_sum(ls, scr) * (1.f / 1024.f);
  float lss = 0.f;
#pragma unroll
  for (int j = 0; j < 4; ++j) {
    const float d = v[j] - mu;
    lss += d * d;
  }
  const float var = block_sum(lss, scr) * (1.f / 1024.f);
  const float rstd = rsqrtf(var + 1e-5f);
  bf16x4 o;
#pragma unroll
  for (int j = 0; j < 4; ++j) {
    const int c = tid * 4 + j;
    const float t = (v[j] - mu) * rstd * g[c] + b[c];
    o[j] = (__bf16)gelu_fast(t);
  }
  *(bf16x4*)(h + row * 1024 + tid * 4) = o;
}

// ---------------- stage C: batched reductions (3 barriered passes) ----------------
__global__ __launch_bounds__(256) void k_stage_c(
    const __bf16* __restrict__ outb, const float* __restrict__ ln_g,
    const float* __restrict__ ln_b, const float* __restrict__ phases,
    const float* __restrict__ temp, float* __restrict__ msq,
    __bf16* __restrict__ mag0, int b0) {
  __shared__ float scr[28];
  const int t = threadIdx.x;
  const long b = blockIdx.x;

  float xa[3][4], xb[3][4];
  float red[6];
#pragma unroll
  for (int s = 0; s < 3; ++s) {
    const __bf16* src = outb + b * 6144 + s * 2048;
    const bf16x4 va = *(const bf16x4*)(src + t * 4);
    const bf16x4 vb = *(const bf16x4*)(src + 1024 + t * 4);
    float sum = 0.f, ssq = 0.f;
#pragma unroll
    for (int j = 0; j < 4; ++j) {
      xa[s][j] = (float)va[j];
      xb[s][j] = (float)vb[j];
      sum += xa[s][j] + xb[s][j];
      ssq += xa[s][j] * xa[s][j] + xb[s][j] * xb[s][j];
    }
    red[2 * s] = sum;
    red[2 * s + 1] = ssq;
  }
  block_sumN<6>(red, scr);

  float ag[3][4], bg[3][4];
  float nsq[3];
#pragma unroll
  for (int s = 0; s < 3; ++s) {
    const float mu = red[2 * s] * (1.f / 2048.f);
    const float var = red[2 * s + 1] * (1.f / 2048.f) - mu * mu;
    const float rstd = rsqrtf(var + 1e-5f);
    const f32x4 ga = *(const f32x4*)(ln_g + s * 2048 + t * 4);
    const f32x4 ba = *(const f32x4*)(ln_b + s * 2048 + t * 4);
    const f32x4 gb = *(const f32x4*)(ln_g + s * 2048 + 1024 + t * 4);
    const f32x4 bb = *(const f32x4*)(ln_b + s * 2048 + 1024 + t * 4);
    float acc = 0.f;
#pragma unroll
    for (int j = 0; j < 4; ++j) {
      const float ya = (xa[s][j] - mu) * rstd * ga[j] + ba[j];
      const float yb = (xb[s][j] - mu) * rstd * gb[j] + bb[j];
      ag[s][j] = __expf(-ya * ya);
      bg[s][j] = __expf(-yb * yb);
      acc += ag[s][j] * ag[s][j] + bg[s][j] * bg[s][j];
    }
    nsq[s] = acc;
  }
  block_sumN<3>(nsq, scr);

  float wr[3][4], wi[3][4];
#pragma unroll
  for (int s = 0; s < 3; ++s) {
    const float factor = sqrtf(2.25f / (nsq[s] + 1e-8f));
    const float ph = phases[s];
    const float cs = __cosf(ph), sn = __sinf(ph);
#pragma unroll
    for (int j = 0; j < 4; ++j) {
      const float a = ag[s][j] * factor;
      const float b2 = bg[s][j] * factor;
      wr[s][j] = a * cs - b2 * sn;
      wi[s][j] = a * sn + b2 * cs;
    }
  }

  float mr[4];
  float dw[7] = {0.f, 0.f, 0.f, 0.f, 0.f, 0.f, 0.f};
#pragma unroll
  for (int j = 0; j < 4; ++j) {
    const float m = (wr[0][j] + wr[1][j] + wr[2][j]) * (1.f / 3.f);
    mr[j] = m;
    dw[6] += m * m;
    dw[0] += wr[0][j] * mr[j]; dw[1] += wr[0][j] * wr[0][j];
    dw[2] += wr[1][j] * mr[j]; dw[3] += wr[1][j] * wr[1][j];
    dw[4] += wr[2][j] * mr[j]; dw[5] += wr[2][j] * wr[2][j];
  }
  block_sumN<7>(dw, scr);
  const float mnorm = sqrtf(dw[6]) + 1e-8f;
  const float T = temp[0];
  const float c0 = dw[0] / ((sqrtf(dw[1]) + 1e-8f) * mnorm) / T;
  const float c1 = dw[2] / ((sqrtf(dw[3]) + 1e-8f) * mnorm) / T;
  const float c2 = dw[4] / ((sqrtf(dw[5]) + 1e-8f) * mnorm) / T;
  const float mx = fmaxf(c0, fmaxf(c1, c2));
  const float e0 = __expf(c0 - mx), e1 = __expf(c1 - mx), e2 = __expf(c2 - mx);
  const float inv = 1.f / (e0 + e1 + e2);
  const float w0 = e0 * inv, w1 = e1 * inv, w2 = e2 * inv;

  const long base = (long)(b0 + b) * 1024 + t * 4;
  f32x4 m2o;
  bf16x4 mgo;
#pragma unroll
  for (int j = 0; j < 4; ++j) {
    const float sr = wr[0][j] * w0 + wr[1][j] * w1 + wr[2][j] * w2;
    const float si = wi[0][j] * w0 + wi[1][j] * w1 + wi[2][j] * w2;
    const float m2 = sr * sr + si * si;
    m2o[j] = m2;
    mgo[j] = (__bf16)sqrtf(m2 + 1e-8f);
  }
  *(f32x4*)(msq + base) = m2o;
  *(bf16x4*)(mag0 + base) = mgo;
}

// ---------------- fused top-8 (u64-key over msq) + sparse cls1 ----------------
__global__ __launch_bounds__(256) void k_topk_cls1(
    const float* __restrict__ msq,
    const float* __restrict__ w1t, const float* __restrict__ b1,
    __bf16* __restrict__ hid) {
  __shared__ u64 candk[32];
  __shared__ u64 selk_s[8];
  __shared__ float ssum_s;
  const int tid = threadIdx.x;
  const int lane = tid & 63;
  const int wv = tid >> 6;
  const long b = blockIdx.x;

  f32x4 mv = *(const f32x4*)(msq + b * 1024 + tid * 4);
  u64 key[4];
#pragma unroll
  for (int j = 0; j < 4; ++j)
    key[j] = ((u64)__float_as_uint(mv[j]) << 32) | (unsigned)(~(unsigned)(tid * 4 + j));
  u64 lm = key[0];
  int jm = 0;
#pragma unroll
  for (int j = 1; j < 4; ++j)
    if (key[j] > lm) { lm = key[j]; jm = j; }

#pragma unroll 1
  for (int it = 0; it < 8; ++it) {
    u64 bk = lm;
#pragma unroll
    for (int m = 1; m < 64; m <<= 1) {
      const u64 ok = __shfl_xor(bk, m, 64);
      bk = ok > bk ? ok : bk;
    }
    if (lane == 0) candk[wv * 8 + it] = bk;
    if (bk == lm) {
      key[jm] = 0ULL;
      lm = key[0]; jm = 0;
#pragma unroll
      for (int j = 1; j < 4; ++j)
        if (key[j] > lm) { lm = key[j]; jm = j; }
    }
  }
  __syncthreads();

  if (wv == 0) {
    u64 ck = (lane < 32) ? candk[lane] : 0ULL;
    float ss = 0.f;
#pragma unroll 1
    for (int it = 0; it < 8; ++it) {
      u64 bk = ck;
#pragma unroll
      for (int m = 1; m < 64; m <<= 1) {
        const u64 ok = __shfl_xor(bk, m, 64);
        bk = ok > bk ? ok : bk;
      }
      if (ck == bk) ck = 0ULL;
      if (lane == 0) {
        selk_s[it] = bk;
        ss += __uint_as_float((unsigned)(bk >> 32));
      }
    }
    if (lane == 0) ssum_s = ss;
  }
  __syncthreads();

  const float denom = 1.f / (ssum_s + 1e-8f);
  float p[8];
  int idx[8];
#pragma unroll
  for (int k = 0; k < 8; ++k) {
    const u64 kk = selk_s[k];
    p[k] = __uint_as_float((unsigned)(kk >> 32)) * denom;
    idx[k] = (int)(~(unsigned)kk & 1023u);
  }

  const int o0 = tid * 4;
  float acc0 = b1[o0], acc1 = b1[o0 + 1], acc2 = b1[o0 + 2], acc3 = b1[o0 + 3];
#pragma unroll
  for (int k = 0; k < 8; ++k) {
    const f32x4 wrow = *(const f32x4*)(w1t + (long)idx[k] * 1024 + o0);
    acc0 += p[k] * wrow[0];
    acc1 += p[k] * wrow[1];
    acc2 += p[k] * wrow[2];
    acc3 += p[k] * wrow[3];
  }
  bf16x4 o = {(__bf16)gelu_fast(acc0), (__bf16)gelu_fast(acc1),
              (__bf16)gelu_fast(acc2), (__bf16)gelu_fast(acc3)};
  *(bf16x4*)(hid + b * 1024 + o0) = o;
}

extern "C" void kernel_launch(void* const* d_in, const int* in_sizes, int n_in,
                              void* d_out, int out_size, void* d_ws, size_t ws_size,
                              hipStream_t stream) {
  const float* x      = (const float*)d_in[0];
  const float* proj_w = (const float*)d_in[1];
  const float* proj_b = (const float*)d_in[2];
  const float* ln_p_g = (const float*)d_in[3];
  const float* ln_p_b = (const float*)d_in[4];
  const float* wf_w   = (const float*)d_in[5];
  const float* wf_b   = (const float*)d_in[6];
  const float* ln_g   = (const float*)d_in[7];
  const float* ln_b   = (const float*)d_in[8];
  const float* temperature = (const float*)d_in[9];
  const float* phases = (const float*)d_in[10];
  const float* gate_w = (const float*)d_in[11];
  const float* gate_b = (const float*)d_in[12];
  const float* cls_w1 = (const float*)d_in[13];
  const float* cls_b1 = (const float*)d_in[14];
  const float* cls_w2 = (const float*)d_in[15];
  const float* cls_b2 = (const float*)d_in[16];
  float* out = (float*)d_out;
  (void)in_sizes; (void)n_in; (void)out_size;

  char* ws = (char*)d_ws;
  const size_t MB = 1024 * 1024;

  if (ws_size >= 196 * MB) {
    // ---- full layout (196MB) ----
    __bf16* xb   = (__bf16*)(ws + 0);
    float*  msq  = (float*)(ws + 0);
    float*  y1   = (float*)(ws + 32 * MB);
    __bf16* mag0 = (__bf16*)(ws + 32 * MB);
    __bf16* mag1 = (__bf16*)(ws + 48 * MB);
    __bf16* outb = (__bf16*)(ws + 64 * MB);
    __bf16* hid  = (__bf16*)(ws + 64 * MB);
    float*  w1t  = (float*)(ws + 96 * MB);
    __bf16* hb   = (__bf16*)(ws + 160 * MB);
    __bf16* wfwb = (__bf16*)(ws + 176 * MB);
    __bf16* gwb  = (__bf16*)(ws + 188 * MB);
    __bf16* c2b  = (__bf16*)(ws + 190 * MB);
    __bf16* w1b  = (__bf16*)(ws + 192 * MB);

    k_cast_bf16<<<16384, 256, 0, stream>>>(x, xb);
    k_cast_weights<<<10240, 256, 0, stream>>>(proj_w, w1b, wf_w, wfwb, gate_w, gwb, cls_w2, c2b);

    k_gemm_bt<0, 64><<<dim3(8, 128), 256, 0, stream>>>(xb, w1b, proj_b, y1, 8192, 1024, 2048, 1024, nullptr, nullptr);
    k_ln_gelu<<<8192, 256, 0, stream>>>(y1, ln_p_g, ln_p_b, hb);

    k_gemm256_bt<<<dim3(24, 32), 512, 0, stream>>>(hb, wfwb, wf_b, outb, 8192, 6144, 1024);
    k_stage_c<<<8192, 256, 0, stream>>>(outb, ln_g, ln_b, phases, temperature, msq, mag0, 0);

    k_transpose1k<<<dim3(32, 32), 256, 0, stream>>>(cls_w1, w1t);
    k_gemm_bt<6, 64><<<dim3(8, 128), 256, 0, stream>>>(mag0, gwb, gate_b, nullptr, 8192, 1024, 1024, 1024, msq, mag1);
    k_gemm_bt<7, 64><<<dim3(8, 128), 256, 0, stream>>>(mag1, gwb, gate_b, nullptr, 8192, 1024, 1024, 1024, msq, nullptr);

    k_topk_cls1<<<8192, 256, 0, stream>>>(msq, w1t, cls_b1, hid);
    k_gemm_bt<0, 64><<<dim3(8, 128), 256, 0, stream>>>(hid, c2b, cls_b2, out, 8192, 1024, 1024, 1000, nullptr, nullptr);
  } else {
    // ---- fallback layout (128MB): 4-chunk G2 path ----
    __bf16* xb   = (__bf16*)(ws + 0);
    float*  msq  = (float*)(ws + 0);
    float*  y1   = (float*)(ws + 32 * MB);
    __bf16* outc = (__bf16*)(ws + 32 * MB);
    __bf16* mag1 = (__bf16*)(ws + 32 * MB);
    __bf16* hid  = (__bf16*)(ws + 48 * MB);
    __bf16* w1b  = (__bf16*)(ws + 64 * MB);
    __bf16* mag0 = (__bf16*)(ws + 64 * MB);
    __bf16* wfwb = (__bf16*)(ws + 96 * MB);
    __bf16* hb   = (__bf16*)(ws + 108 * MB);
    float*  w1t  = (float*)(ws + 108 * MB);
    __bf16* gwb  = (__bf16*)(ws + 124 * MB);
    __bf16* c2b  = (__bf16*)(ws + 126 * MB);

    k_cast_bf16<<<16384, 256, 0, stream>>>(x, xb);
    k_cast_weights<<<10240, 256, 0, stream>>>(proj_w, w1b, wf_w, wfwb, gate_w, gwb, cls_w2, c2b);

    k_gemm_bt<0, 64><<<dim3(8, 128), 256, 0, stream>>>(xb, w1b, proj_b, y1, 8192, 1024, 2048, 1024, nullptr, nullptr);
    k_ln_gelu<<<8192, 256, 0, stream>>>(y1, ln_p_g, ln_p_b, hb);

    for (int c = 0; c < 4; ++c) {
      k_gemm_bt<1, 128><<<dim3(48, 16), 256, 0, stream>>>(hb + (size_t)c * 2048 * 1024, wfwb, wf_b,
                                                          outc, 2048, 6144, 1024, 6144, nullptr, nullptr);
      k_stage_c<<<2048, 256, 0, stream>>>(outc, ln_g, ln_b, phases, temperature,
                                          msq, mag0, c * 2048);
    }

    k_transpose1k<<<dim3(32, 32), 256, 0, stream>>>(cls_w1, w1t);
    k_gemm_bt<6, 64><<<dim3(8, 128), 256, 0, stream>>>(mag0, gwb, gate_b, nullptr, 8192, 1024, 1024, 1024, msq, mag1);
    k_gemm_bt<7, 64><<<dim3(8, 128), 256, 0, stream>>>(mag1, gwb, gate_b, nullptr, 8192, 1024, 1024, 1024, msq, nullptr);

    k_topk_cls1<<<8192, 256, 0, stream>>>(msq, w1t, cls_b1, hid);
    k_gemm_bt<0, 64><<<dim3(8, 128), 256, 0, stream>>>(hid, c2b, cls_b2, out, 8192, 1024, 1024, 1000, nullptr, nullptr);
  }
}

// Round 21
// 432.493 us; speedup vs baseline: 1.0866x; 1.0086x over previous
//
#include <hip/hip_runtime.h>
#include <cstdint>

typedef __attribute__((ext_vector_type(8))) __bf16 bf16x8;
typedef __attribute__((ext_vector_type(4))) __bf16 bf16x4;
typedef __attribute__((ext_vector_type(4))) float f32x4;
typedef unsigned long long u64;

__device__ __forceinline__ void gld_lds16(const void* g, void* l) {
  __builtin_amdgcn_global_load_lds(
      (const __attribute__((address_space(1))) void*)g,
      (__attribute__((address_space(3))) void*)l, 16, 0, 0);
}

__device__ __forceinline__ float block_sum(float v, float* scr) {
#pragma unroll
  for (int off = 32; off > 0; off >>= 1) v += __shfl_down(v, off, 64);
  const int w = threadIdx.x >> 6;
  __syncthreads();
  if ((threadIdx.x & 63) == 0) scr[w] = v;
  __syncthreads();
  float s = 0.f;
  const int nw = blockDim.x >> 6;
  for (int i = 0; i < nw; ++i) s += scr[i];
  return s;
}

// fused N-value block reduction (256 threads = 4 waves), scr size >= 4*N
template <int N>
__device__ __forceinline__ void block_sumN(float* v, float* scr) {
#pragma unroll
  for (int i = 0; i < N; ++i)
#pragma unroll
    for (int m = 1; m < 64; m <<= 1) v[i] += __shfl_xor(v[i], m, 64);
  const int w = threadIdx.x >> 6;
  __syncthreads();
  if ((threadIdx.x & 63) == 0)
#pragma unroll
    for (int i = 0; i < N; ++i) scr[w * N + i] = v[i];
  __syncthreads();
#pragma unroll
  for (int i = 0; i < N; ++i) {
    float s = 0.f;
    for (int ww = 0; ww < 4; ++ww) s += scr[ww * N + i];
    v[i] = s;
  }
}

// fast gelu: A&S 7.1.26 erf (|err|<1.5e-7) + hw exp
__device__ __forceinline__ float gelu_fast(float x) {
  const float ax = fabsf(x) * 0.70710678118654752f;
  const float t = 1.f / (1.f + 0.3275911f * ax);
  const float e = __expf(-ax * ax);
  float poly = 1.061405429f;
  poly = poly * t - 1.453152027f;
  poly = poly * t + 1.421413741f;
  poly = poly * t - 0.284496736f;
  poly = poly * t + 0.254829592f;
  const float erfax = 1.f - poly * t * e;
  const float er = copysignf(erfax, x);
  return 0.5f * x * (1.f + er);
}

// combined casts: x(16384) | proj_w(2048) | wf_w(6144) | gate_w(1024) | cls_w2 pad(1024)
__global__ __launch_bounds__(256) void k_cast_all(
    const float* __restrict__ x, __bf16* __restrict__ xb,
    const float* __restrict__ pw, __bf16* __restrict__ w1b,
    const float* __restrict__ wfw, __bf16* __restrict__ wfwb,
    const float* __restrict__ gw, __bf16* __restrict__ gwb,
    const float* __restrict__ c2, __bf16* __restrict__ c2b) {
  const int bid = blockIdx.x;
  if (bid >= 25600) {
    // cls_w2: 1000x1024 -> 1024x1024 zero-padded
    const long i = ((long)(bid - 25600) * 256 + threadIdx.x) * 4;
    const int row = (int)(i >> 10);
    const int col = (int)(i & 1023);
    bf16x4 o;
    if (row < 1000) {
      f32x4 v = *(const f32x4*)(c2 + (long)row * 1024 + col);
      o = (bf16x4){(__bf16)v[0], (__bf16)v[1], (__bf16)v[2], (__bf16)v[3]};
    } else {
      o = (bf16x4){(__bf16)0.f, (__bf16)0.f, (__bf16)0.f, (__bf16)0.f};
    }
    *(bf16x4*)(c2b + i) = o;
    return;
  }
  const float* in;
  __bf16* out;
  long base;
  if (bid < 16384) { in = x; out = xb; base = (long)bid * 1024; }
  else if (bid < 18432) { in = pw; out = w1b; base = (long)(bid - 16384) * 1024; }
  else if (bid < 24576) { in = wfw; out = wfwb; base = (long)(bid - 18432) * 1024; }
  else { in = gw; out = gwb; base = (long)(bid - 24576) * 1024; }
  const long i = base + threadIdx.x * 4;
  f32x4 v = *(const f32x4*)(in + i);
  bf16x4 o = {(__bf16)v[0], (__bf16)v[1], (__bf16)v[2], (__bf16)v[3]};
  *(bf16x4*)(out + i) = o;
}

// ---------------- transpose 1024x1024 f32 ----------------
__global__ __launch_bounds__(256) void k_transpose1k(const float* __restrict__ in,
                                                     float* __restrict__ out) {
  __shared__ float t[32][33];
  const int tx = threadIdx.x & 31;
  const int ty = threadIdx.x >> 5;
  const int r0 = blockIdx.y * 32, c0 = blockIdx.x * 32;
#pragma unroll
  for (int k = 0; k < 4; ++k)
    t[ty + 8 * k][tx] = in[(long)(r0 + ty + 8 * k) * 1024 + c0 + tx];
  __syncthreads();
#pragma unroll
  for (int k = 0; k < 4; ++k)
    out[(long)(c0 + ty + 8 * k) * 1024 + r0 + tx] = t[tx][ty + 8 * k];
}

// ============ 256x256 8-wave BK=64 GEMM (R14/R17 proven) ============
__global__ __launch_bounds__(512, 1) void k_gemm256_bt(
    const __bf16* __restrict__ A, const __bf16* __restrict__ B,
    const float* __restrict__ bias, __bf16* __restrict__ C,
    int M, int N, int K) {
  __shared__ __align__(16) __bf16 lds[2][2][256 * 64];  // [slot][mat][row*64+k]
  const int tid = threadIdx.x;
  const int lane = tid & 63;
  const int wid = tid >> 6;
  const int wr = wid >> 2;
  const int wc = wid & 3;
  const int gx = gridDim.x, gy = gridDim.y;
  const int lin = blockIdx.y * gx + blockIdx.x;
  const int xcd = lin & 7;
  const int local = lin >> 3;
  const int byq = gy >> 3;
  const int bx = local / byq;
  const int by = xcd * byq + (local % byq);
  const int m0 = by * 256, n0 = bx * 256;
  const int fr = lane & 15;
  const int fx = lane >> 4;
  const int px = lane & 7;

  const __bf16* Abase = A + (long)m0 * K;
  const __bf16* Bbase = B + (long)n0 * K;

  auto stage_q = [&](int slot, int kt, int mat, int half) {
    const __bf16* src = (mat ? Bbase : Abase) + kt * 64;
#pragma unroll
    for (int q = 0; q < 2; ++q) {
      const int idx = q * 512 + tid;
      const int r = idx >> 3;
      const int pblk = idx & 7;
      const int row = half * 128 + r;
      const int lblk = pblk ^ (r & 7);
      gld_lds16(src + (long)row * K + lblk * 8,
                (char*)&lds[slot][mat][row * 64 + pblk * 8]);
    }
  };
  auto frag = [&](int slot, int mat, int row, int ks) -> bf16x8 {
    return *(const bf16x8*)&lds[slot][mat][row * 64 + ((((ks << 2) + fx) ^ px) << 3)];
  };

  f32x4 acc[8][4] = {};
  const int nt = K >> 6;
#pragma unroll
  for (int qp = 0; qp < 4; ++qp) stage_q(0, 0, qp >> 1, qp & 1);

  const int arow = wr * 128 + fr;
  const int brow = wc * 64 + fr;

  for (int t = 0; t < nt; ++t) {
    const int sc = t & 1, sn = sc ^ 1;
    if (t + 1 < nt) {
#pragma unroll
      for (int qp = 0; qp < 4; ++qp) stage_q(sn, t + 1, qp >> 1, qp & 1);
      asm volatile("s_waitcnt vmcnt(8)" ::: "memory");
    } else {
      asm volatile("s_waitcnt vmcnt(0)" ::: "memory");
    }
    __builtin_amdgcn_sched_barrier(0);
    __builtin_amdgcn_s_barrier();
    bf16x8 b0[4], b1[4];
#pragma unroll
    for (int j = 0; j < 4; ++j) {
      b0[j] = frag(sc, 1, brow + j * 16, 0);
      b1[j] = frag(sc, 1, brow + j * 16, 1);
    }
    __builtin_amdgcn_s_setprio(1);
#pragma unroll
    for (int im = 0; im < 8; ++im) {
      bf16x8 x0 = frag(sc, 0, arow + im * 16, 0);
      bf16x8 x1 = frag(sc, 0, arow + im * 16, 1);
#pragma unroll
      for (int j = 0; j < 4; ++j) {
        acc[im][j] = __builtin_amdgcn_mfma_f32_16x16x32_bf16(x0, b0[j], acc[im][j], 0, 0, 0);
        acc[im][j] = __builtin_amdgcn_mfma_f32_16x16x32_bf16(x1, b1[j], acc[im][j], 0, 0, 0);
      }
    }
    __builtin_amdgcn_s_setprio(0);
    __builtin_amdgcn_s_barrier();
  }

  // ---- epilogue: bounce C tile through dead staging LDS ----
  __bf16* cb = (__bf16*)&lds[0][0][0];
  const int lm0 = wr * 128 + fx * 4;
  const int lc0 = wc * 64 + fr;
#pragma unroll
  for (int j = 0; j < 4; ++j) {
    const float bv = bias[n0 + lc0 + j * 16];
#pragma unroll
    for (int im = 0; im < 8; ++im)
#pragma unroll
      for (int r = 0; r < 4; ++r)
        cb[(lm0 + im * 16 + r) * 256 + lc0 + j * 16] = (__bf16)(acc[im][j][r] + bv);
  }
  __syncthreads();
#pragma unroll
  for (int q = 0; q < 16; ++q) {
    const int idx = q * 512 + tid;
    const int row = idx >> 5;
    const int c8 = (idx & 31) * 8;
    *(f32x4*)(C + (long)(m0 + row) * N + n0 + c8) = *(const f32x4*)(cb + row * 256 + c8);
  }
}

// ---------------- GEMM: C = A @ B^T + bias (128-col tiles) ----------------
// A-resident XCD partition when gy%8==0 (else legacy swizzle).
// EPI: 0 f32 store (LDS-bounce full-line), 1 bf16 store (scatter; fallback),
//      6 gate1: msq *= f^2 streaming + mag bf16 out, 7 gate2: msq *= f^2 streaming
template <int EPI, int BM>
__global__ __launch_bounds__(256) void k_gemm_bt(
    const __bf16* __restrict__ A, const __bf16* __restrict__ B,
    const float* __restrict__ bias, void* __restrict__ Cout,
    int M, int N, int K, int Nreal,
    float* __restrict__ msq, __bf16* __restrict__ magOut) {
  constexpr int MR = BM / 32;
  constexpr int STAGE_B = (2 * BM * 32 + 2 * 128 * 32) * 2;
  constexpr int CB_B = BM * 64 * 4;
  constexpr int SMEM_B = STAGE_B > CB_B ? STAGE_B : CB_B;
  __shared__ __align__(16) char smem[SMEM_B];
  __bf16* As = (__bf16*)smem;
  __bf16* Bs = (__bf16*)(smem + (size_t)2 * BM * 32 * 2);
  float* cb = (float*)smem;  // bounce region (BM x 64 f32)
  const int tid = threadIdx.x;
  const int lane = tid & 63;
  const int wid = tid >> 6;
  const int wr = wid >> 1, wc = wid & 1;

  const int gx = gridDim.x, gy = gridDim.y;
  const int nwg = gx * gy;
  int bx, by;
  if ((gy & 7) == 0) {
    const int lin = blockIdx.y * gx + blockIdx.x;
    const int xcd = lin & 7;
    const int local = lin >> 3;
    const int byq = gy >> 3;
    bx = local / byq;
    by = xcd * byq + (local % byq);
  } else if ((nwg & 7) == 0) {
    const int lin = blockIdx.y * gx + blockIdx.x;
    const int cpx = nwg >> 3;
    const int w = (lin & 7) * cpx + (lin >> 3);
    bx = w / gy;
    by = w % gy;
  } else {
    bx = blockIdx.x;
    by = blockIdx.y;
  }
  const int m0 = by * BM;
  const int n0 = bx * 128;
  const int frow = lane & 15;
  const int fk = (lane >> 4) * 8;
  f32x4 acc[MR][4] = {};

  auto stage = [&](int buf, int k0) {
    const __bf16* Ab = A + (long)m0 * K + k0;
    const __bf16* Bb = B + (long)n0 * K + k0;
    __bf16* Asb = As + buf * BM * 32;
    __bf16* Bsb = Bs + buf * 128 * 32;
#pragma unroll
    for (int q = 0; q < BM / 64; ++q) {
      const int idx = q * 256 + tid;
      const int row = idx >> 2;
      const int col = (idx & 3) * 8;
      gld_lds16(Ab + (long)row * K + col, (char*)Asb + idx * 16);
    }
#pragma unroll
    for (int q = 0; q < 2; ++q) {
      const int idx = q * 256 + tid;
      const int row = idx >> 2;
      const int col = (idx & 3) * 8;
      gld_lds16(Bb + (long)row * K + col, (char*)Bsb + idx * 16);
    }
  };

  const int nt = K >> 5;
  int cur = 0;
  stage(0, 0);
  __syncthreads();
  for (int t = 0; t < nt; ++t) {
    if (t + 1 < nt) stage(cur ^ 1, (t + 1) << 5);
    bf16x8 af[MR], bfr[4];
#pragma unroll
    for (int i = 0; i < MR; ++i)
      af[i] = *(const bf16x8*)(As + cur * BM * 32 + (wr * (BM / 2) + i * 16 + frow) * 32 + fk);
#pragma unroll
    for (int i = 0; i < 4; ++i)
      bfr[i] = *(const bf16x8*)(Bs + cur * 128 * 32 + (wc * 64 + i * 16 + frow) * 32 + fk);
#pragma unroll
    for (int im = 0; im < MR; ++im)
#pragma unroll
      for (int in = 0; in < 4; ++in)
        acc[im][in] = __builtin_amdgcn_mfma_f32_16x16x32_bf16(af[im], bfr[in],
                                                              acc[im][in], 0, 0, 0);
    __syncthreads();
    cur ^= 1;
  }

  if (EPI == 0 || EPI == 6 || EPI == 7) {
#pragma unroll 1
    for (int h = 0; h < 2; ++h) {
      __syncthreads();
      if (wc == h) {
#pragma unroll
        for (int in = 0; in < 4; ++in) {
          const int col = n0 + h * 64 + in * 16 + frow;
          const float bv = (col < Nreal) ? bias[col] : 0.f;
          const int lcc = in * 16 + frow;
#pragma unroll
          for (int im = 0; im < MR; ++im)
#pragma unroll
            for (int r = 0; r < 4; ++r) {
              const float v = acc[im][in][r] + bv;
              float sv;
              if (EPI == 0) {
                sv = v;
              } else {
                const float f = 1.f / (1.f + __expf(-v)) + 0.1f;
                sv = f * f;
              }
              cb[(wr * (BM / 2) + (lane >> 4) * 4 + im * 16 + r) * 64 + lcc] = sv;
            }
        }
      }
      __syncthreads();
#pragma unroll
      for (int q = 0; q < BM / 16; ++q) {
        const int idx = q * 256 + tid;
        const int row = idx >> 4;
        const int c4 = (idx & 15) * 4;
        const int gc = n0 + h * 64 + c4;
        if (EPI == 0) {
          if (gc < Nreal)
            *(f32x4*)((float*)Cout + (long)(m0 + row) * Nreal + gc) =
                *(const f32x4*)(cb + row * 64 + c4);
        } else {
          const long gix = (long)(m0 + row) * Nreal + gc;
          f32x4 m = *(const f32x4*)(msq + gix);
          const f32x4 f2 = *(const f32x4*)(cb + row * 64 + c4);
          m[0] *= f2[0]; m[1] *= f2[1]; m[2] *= f2[2]; m[3] *= f2[3];
          *(f32x4*)(msq + gix) = m;
          if (EPI == 6) {
            bf16x4 mg = {(__bf16)sqrtf(m[0] + 1e-8f), (__bf16)sqrtf(m[1] + 1e-8f),
                         (__bf16)sqrtf(m[2] + 1e-8f), (__bf16)sqrtf(m[3] + 1e-8f)};
            *(bf16x4*)(magOut + gix) = mg;
          }
        }
      }
    }
  } else {
    const int crow0 = m0 + wr * (BM / 2) + (lane >> 4) * 4;
    const int ccol0 = n0 + wc * 64 + (lane & 15);
#pragma unroll
    for (int in = 0; in < 4; ++in) {
      const int col = ccol0 + in * 16;
      if (col >= Nreal) continue;
      const float bv = bias[col];
#pragma unroll
      for (int im = 0; im < MR; ++im) {
#pragma unroll
        for (int r = 0; r < 4; ++r) {
          const long row = crow0 + im * 16 + r;
          ((__bf16*)Cout)[row * Nreal + col] = (__bf16)(acc[im][in][r] + bv);
        }
      }
    }
  }
}

// ---------------- LN (over 1024) + gelu -> bf16 ----------------
__global__ __launch_bounds__(256) void k_ln_gelu(const float* __restrict__ y,
                                                 const float* __restrict__ g,
                                                 const float* __restrict__ b,
                                                 __bf16* __restrict__ h) {
  __shared__ float scr[8];
  const int tid = threadIdx.x;
  const long row = blockIdx.x;
  const float* yr = y + row * 1024;
  f32x4 v = *(const f32x4*)(yr + tid * 4);
  float ls = v[0] + v[1] + v[2] + v[3];
  const float mu = block_sum(ls, scr) * (1.f / 1024.f);
  float lss = 0.f;
#pragma unroll
  for (int j = 0; j < 4; ++j) {
    const float d = v[j] - mu;
    lss += d * d;
  }
  const float var = block_sum(lss, scr) * (1.f / 1024.f);
  const float rstd = rsqrtf(var + 1e-5f);
  bf16x4 o;
#pragma unroll
  for (int j = 0; j < 4; ++j) {
    const int c = tid * 4 + j;
    const float t = (v[j] - mu) * rstd * g[c] + b[c];
    o[j] = (__bf16)gelu_fast(t);
  }
  *(bf16x4*)(h + row * 1024 + tid * 4) = o;
}

// ---------------- stage C: batched reductions (3 barriered passes) ----------------
__global__ __launch_bounds__(256) void k_stage_c(
    const __bf16* __restrict__ outb, const float* __restrict__ ln_g,
    const float* __restrict__ ln_b, const float* __restrict__ phases,
    const float* __restrict__ temp, float* __restrict__ msq,
    __bf16* __restrict__ mag0, int b0) {
  __shared__ float scr[28];
  const int t = threadIdx.x;
  const long b = blockIdx.x;

  float xa[3][4], xb[3][4];
  float red[6];
#pragma unroll
  for (int s = 0; s < 3; ++s) {
    const __bf16* src = outb + b * 6144 + s * 2048;
    const bf16x4 va = *(const bf16x4*)(src + t * 4);
    const bf16x4 vb = *(const bf16x4*)(src + 1024 + t * 4);
    float sum = 0.f, ssq = 0.f;
#pragma unroll
    for (int j = 0; j < 4; ++j) {
      xa[s][j] = (float)va[j];
      xb[s][j] = (float)vb[j];
      sum += xa[s][j] + xb[s][j];
      ssq += xa[s][j] * xa[s][j] + xb[s][j] * xb[s][j];
    }
    red[2 * s] = sum;
    red[2 * s + 1] = ssq;
  }
  block_sumN<6>(red, scr);

  float ag[3][4], bg[3][4];
  float nsq[3];
#pragma unroll
  for (int s = 0; s < 3; ++s) {
    const float mu = red[2 * s] * (1.f / 2048.f);
    const float var = red[2 * s + 1] * (1.f / 2048.f) - mu * mu;
    const float rstd = rsqrtf(var + 1e-5f);
    const f32x4 ga = *(const f32x4*)(ln_g + s * 2048 + t * 4);
    const f32x4 ba = *(const f32x4*)(ln_b + s * 2048 + t * 4);
    const f32x4 gb = *(const f32x4*)(ln_g + s * 2048 + 1024 + t * 4);
    const f32x4 bb = *(const f32x4*)(ln_b + s * 2048 + 1024 + t * 4);
    float acc = 0.f;
#pragma unroll
    for (int j = 0; j < 4; ++j) {
      const float ya = (xa[s][j] - mu) * rstd * ga[j] + ba[j];
      const float yb = (xb[s][j] - mu) * rstd * gb[j] + bb[j];
      ag[s][j] = __expf(-ya * ya);
      bg[s][j] = __expf(-yb * yb);
      acc += ag[s][j] * ag[s][j] + bg[s][j] * bg[s][j];
    }
    nsq[s] = acc;
  }
  block_sumN<3>(nsq, scr);

  float wr[3][4], wi[3][4];
#pragma unroll
  for (int s = 0; s < 3; ++s) {
    const float factor = sqrtf(2.25f / (nsq[s] + 1e-8f));
    const float ph = phases[s];
    const float cs = __cosf(ph), sn = __sinf(ph);
#pragma unroll
    for (int j = 0; j < 4; ++j) {
      const float a = ag[s][j] * factor;
      const float b2 = bg[s][j] * factor;
      wr[s][j] = a * cs - b2 * sn;
      wi[s][j] = a * sn + b2 * cs;
    }
  }

  float mr[4];
  float dw[7] = {0.f, 0.f, 0.f, 0.f, 0.f, 0.f, 0.f};
#pragma unroll
  for (int j = 0; j < 4; ++j) {
    const float m = (wr[0][j] + wr[1][j] + wr[2][j]) * (1.f / 3.f);
    mr[j] = m;
    dw[6] += m * m;
    dw[0] += wr[0][j] * mr[j]; dw[1] += wr[0][j] * wr[0][j];
    dw[2] += wr[1][j] * mr[j]; dw[3] += wr[1][j] * wr[1][j];
    dw[4] += wr[2][j] * mr[j]; dw[5] += wr[2][j] * wr[2][j];
  }
  block_sumN<7>(dw, scr);
  const float mnorm = sqrtf(dw[6]) + 1e-8f;
  const float T = temp[0];
  const float c0 = dw[0] / ((sqrtf(dw[1]) + 1e-8f) * mnorm) / T;
  const float c1 = dw[2] / ((sqrtf(dw[3]) + 1e-8f) * mnorm) / T;
  const float c2 = dw[4] / ((sqrtf(dw[5]) + 1e-8f) * mnorm) / T;
  const float mx = fmaxf(c0, fmaxf(c1, c2));
  const float e0 = __expf(c0 - mx), e1 = __expf(c1 - mx), e2 = __expf(c2 - mx);
  const float inv = 1.f / (e0 + e1 + e2);
  const float w0 = e0 * inv, w1 = e1 * inv, w2 = e2 * inv;

  const long base = (long)(b0 + b) * 1024 + t * 4;
  f32x4 m2o;
  bf16x4 mgo;
#pragma unroll
  for (int j = 0; j < 4; ++j) {
    const float sr = wr[0][j] * w0 + wr[1][j] * w1 + wr[2][j] * w2;
    const float si = wi[0][j] * w0 + wi[1][j] * w1 + wi[2][j] * w2;
    const float m2 = sr * sr + si * si;
    m2o[j] = m2;
    mgo[j] = (__bf16)sqrtf(m2 + 1e-8f);
  }
  *(f32x4*)(msq + base) = m2o;
  *(bf16x4*)(mag0 + base) = mgo;
}

// ---------------- fused top-8 (u64-key over msq) + sparse cls1 ----------------
__global__ __launch_bounds__(256) void k_topk_cls1(
    const float* __restrict__ msq,
    const float* __restrict__ w1t, const float* __restrict__ b1,
    __bf16* __restrict__ hid) {
  __shared__ u64 candk[32];
  __shared__ u64 selk_s[8];
  __shared__ float ssum_s;
  const int tid = threadIdx.x;
  const int lane = tid & 63;
  const int wv = tid >> 6;
  const long b = blockIdx.x;

  f32x4 mv = *(const f32x4*)(msq + b * 1024 + tid * 4);
  u64 key[4];
#pragma unroll
  for (int j = 0; j < 4; ++j)
    key[j] = ((u64)__float_as_uint(mv[j]) << 32) | (unsigned)(~(unsigned)(tid * 4 + j));
  u64 lm = key[0];
  int jm = 0;
#pragma unroll
  for (int j = 1; j < 4; ++j)
    if (key[j] > lm) { lm = key[j]; jm = j; }

#pragma unroll 1
  for (int it = 0; it < 8; ++it) {
    u64 bk = lm;
#pragma unroll
    for (int m = 1; m < 64; m <<= 1) {
      const u64 ok = __shfl_xor(bk, m, 64);
      bk = ok > bk ? ok : bk;
    }
    if (lane == 0) candk[wv * 8 + it] = bk;
    if (bk == lm) {
      key[jm] = 0ULL;
      lm = key[0]; jm = 0;
#pragma unroll
      for (int j = 1; j < 4; ++j)
        if (key[j] > lm) { lm = key[j]; jm = j; }
    }
  }
  __syncthreads();

  if (wv == 0) {
    u64 ck = (lane < 32) ? candk[lane] : 0ULL;
    float ss = 0.f;
#pragma unroll 1
    for (int it = 0; it < 8; ++it) {
      u64 bk = ck;
#pragma unroll
      for (int m = 1; m < 64; m <<= 1) {
        const u64 ok = __shfl_xor(bk, m, 64);
        bk = ok > bk ? ok : bk;
      }
      if (ck == bk) ck = 0ULL;
      if (lane == 0) {
        selk_s[it] = bk;
        ss += __uint_as_float((unsigned)(bk >> 32));
      }
    }
    if (lane == 0) ssum_s = ss;
  }
  __syncthreads();

  const float denom = 1.f / (ssum_s + 1e-8f);
  float p[8];
  int idx[8];
#pragma unroll
  for (int k = 0; k < 8; ++k) {
    const u64 kk = selk_s[k];
    p[k] = __uint_as_float((unsigned)(kk >> 32)) * denom;
    idx[k] = (int)(~(unsigned)kk & 1023u);
  }

  const int o0 = tid * 4;
  float acc0 = b1[o0], acc1 = b1[o0 + 1], acc2 = b1[o0 + 2], acc3 = b1[o0 + 3];
#pragma unroll
  for (int k = 0; k < 8; ++k) {
    const f32x4 wrow = *(const f32x4*)(w1t + (long)idx[k] * 1024 + o0);
    acc0 += p[k] * wrow[0];
    acc1 += p[k] * wrow[1];
    acc2 += p[k] * wrow[2];
    acc3 += p[k] * wrow[3];
  }
  bf16x4 o = {(__bf16)gelu_fast(acc0), (__bf16)gelu_fast(acc1),
              (__bf16)gelu_fast(acc2), (__bf16)gelu_fast(acc3)};
  *(bf16x4*)(hid + b * 1024 + o0) = o;
}

extern "C" void kernel_launch(void* const* d_in, const int* in_sizes, int n_in,
                              void* d_out, int out_size, void* d_ws, size_t ws_size,
                              hipStream_t stream) {
  const float* x      = (const float*)d_in[0];
  const float* proj_w = (const float*)d_in[1];
  const float* proj_b = (const float*)d_in[2];
  const float* ln_p_g = (const float*)d_in[3];
  const float* ln_p_b = (const float*)d_in[4];
  const float* wf_w   = (const float*)d_in[5];
  const float* wf_b   = (const float*)d_in[6];
  const float* ln_g   = (const float*)d_in[7];
  const float* ln_b   = (const float*)d_in[8];
  const float* temperature = (const float*)d_in[9];
  const float* phases = (const float*)d_in[10];
  const float* gate_w = (const float*)d_in[11];
  const float* gate_b = (const float*)d_in[12];
  const float* cls_w1 = (const float*)d_in[13];
  const float* cls_b1 = (const float*)d_in[14];
  const float* cls_w2 = (const float*)d_in[15];
  const float* cls_b2 = (const float*)d_in[16];
  float* out = (float*)d_out;
  (void)in_sizes; (void)n_in; (void)out_size;

  char* ws = (char*)d_ws;
  const size_t MB = 1024 * 1024;

  if (ws_size >= 196 * MB) {
    // ---- full layout (196MB) ----
    __bf16* xb   = (__bf16*)(ws + 0);
    float*  msq  = (float*)(ws + 0);
    float*  y1   = (float*)(ws + 32 * MB);
    __bf16* mag0 = (__bf16*)(ws + 32 * MB);
    __bf16* mag1 = (__bf16*)(ws + 48 * MB);
    __bf16* outb = (__bf16*)(ws + 64 * MB);
    __bf16* hid  = (__bf16*)(ws + 64 * MB);
    float*  w1t  = (float*)(ws + 96 * MB);
    __bf16* hb   = (__bf16*)(ws + 160 * MB);
    __bf16* wfwb = (__bf16*)(ws + 176 * MB);
    __bf16* gwb  = (__bf16*)(ws + 188 * MB);
    __bf16* c2b  = (__bf16*)(ws + 190 * MB);
    __bf16* w1b  = (__bf16*)(ws + 192 * MB);

    k_cast_all<<<26624, 256, 0, stream>>>(x, xb, proj_w, w1b, wf_w, wfwb, gate_w, gwb, cls_w2, c2b);

    k_gemm_bt<0, 64><<<dim3(8, 128), 256, 0, stream>>>(xb, w1b, proj_b, y1, 8192, 1024, 2048, 1024, nullptr, nullptr);
    k_ln_gelu<<<8192, 256, 0, stream>>>(y1, ln_p_g, ln_p_b, hb);

    k_gemm256_bt<<<dim3(24, 32), 512, 0, stream>>>(hb, wfwb, wf_b, outb, 8192, 6144, 1024);
    k_stage_c<<<8192, 256, 0, stream>>>(outb, ln_g, ln_b, phases, temperature, msq, mag0, 0);

    k_transpose1k<<<dim3(32, 32), 256, 0, stream>>>(cls_w1, w1t);
    k_gemm_bt<6, 64><<<dim3(8, 128), 256, 0, stream>>>(mag0, gwb, gate_b, nullptr, 8192, 1024, 1024, 1024, msq, mag1);
    k_gemm_bt<7, 64><<<dim3(8, 128), 256, 0, stream>>>(mag1, gwb, gate_b, nullptr, 8192, 1024, 1024, 1024, msq, nullptr);

    k_topk_cls1<<<8192, 256, 0, stream>>>(msq, w1t, cls_b1, hid);
    k_gemm_bt<0, 64><<<dim3(8, 128), 256, 0, stream>>>(hid, c2b, cls_b2, out, 8192, 1024, 1024, 1000, nullptr, nullptr);
  } else {
    // ---- fallback layout (128MB): 4-chunk G2 path ----
    __bf16* xb   = (__bf16*)(ws + 0);
    float*  msq  = (float*)(ws + 0);
    float*  y1   = (float*)(ws + 32 * MB);
    __bf16* outc = (__bf16*)(ws + 32 * MB);
    __bf16* mag1 = (__bf16*)(ws + 32 * MB);
    __bf16* hid  = (__bf16*)(ws + 48 * MB);
    __bf16* w1b  = (__bf16*)(ws + 64 * MB);
    __bf16* mag0 = (__bf16*)(ws + 64 * MB);
    __bf16* wfwb = (__bf16*)(ws + 96 * MB);
    __bf16* hb   = (__bf16*)(ws + 108 * MB);
    float*  w1t  = (float*)(ws + 108 * MB);
    __bf16* gwb  = (__bf16*)(ws + 124 * MB);
    __bf16* c2b  = (__bf16*)(ws + 126 * MB);

    k_cast_all<<<26624, 256, 0, stream>>>(x, xb, proj_w, w1b, wf_w, wfwb, gate_w, gwb, cls_w2, c2b);

    k_gemm_bt<0, 64><<<dim3(8, 128), 256, 0, stream>>>(xb, w1b, proj_b, y1, 8192, 1024, 2048, 1024, nullptr, nullptr);
    k_ln_gelu<<<8192, 256, 0, stream>>>(y1, ln_p_g, ln_p_b, hb);

    for (int c = 0; c < 4; ++c) {
      k_gemm_bt<1, 128><<<dim3(48, 16), 256, 0, stream>>>(hb + (size_t)c * 2048 * 1024, wfwb, wf_b,
                                                          outc, 2048, 6144, 1024, 6144, nullptr, nullptr);
      k_stage_c<<<2048, 256, 0, stream>>>(outc, ln_g, ln_b, phases, temperature,
                                          msq, mag0, c * 2048);
    }

    k_transpose1k<<<dim3(32, 32), 256, 0, stream>>>(cls_w1, w1t);
    k_gemm_bt<6, 64><<<dim3(8, 128), 256, 0, stream>>>(mag0, gwb, gate_b, nullptr, 8192, 1024, 1024, 1024, msq, mag1);
    k_gemm_bt<7, 64><<<dim3(8, 128), 256, 0, stream>>>(mag1, gwb, gate_b, nullptr, 8192, 1024, 1024, 1024, msq, nullptr);

    k_topk_cls1<<<8192, 256, 0, stream>>>(msq, w1t, cls_b1, hid);
    k_gemm_bt<0, 64><<<dim3(8, 128), 256, 0, stream>>>(hid, c2b, cls_b2, out, 8192, 1024, 1024, 1000, nullptr, nullptr);
  }
}